// Round 7
// baseline (106513.123 us; speedup 1.0000x reference)
//
#include <hip/hip_runtime.h>

#define D_ 512
#define H_ 1024
#define L_ 4096
#define CS_ 64
#define NCH_ 64
#define RACT_ 256
#define LR_ 0.1f
#define MOM_ 0.95f
#define NSA_ 3.4445f
#define NSB_ (-4.7750f)
#define NSC_ 2.0315f

#define TPB2_ 256  // 4 waves
#define MSZ_ ((size_t)D_ * H_)
#define ASZ_ ((size_t)D_ * D_)

using bf16x8 = __attribute__((ext_vector_type(8))) short;
using f32x4  = __attribute__((ext_vector_type(4))) float;
using s16x4  = __attribute__((ext_vector_type(4))) short;

__device__ __forceinline__ short f2bs(float f) {
  unsigned u = __builtin_bit_cast(unsigned, f);
  unsigned r = (u + 0x7fffu + ((u >> 16) & 1u)) >> 16;  // RNE
  return (short)r;
}
__device__ __forceinline__ float bs2f(short s) {
  unsigned u = ((unsigned)(unsigned short)s) << 16;
  return __builtin_bit_cast(float, u);
}
__device__ __forceinline__ void split2(float v, short& h, short& l) {
  h = f2bs(v);
  l = f2bs(v - bs2f(h));
}

#define MFMA16(a, b, c) __builtin_amdgcn_mfma_f32_16x16x32_bf16(a, b, c, 0, 0, 0)

// Split-bf16 NT GEMM, one 32x32 output tile, 4 waves split K 4 ways.
// Partials to LDS, deterministic 4-way fp32 sum. Returns 4 consecutive
// outputs per thread at (row, c0..c0+3).
template <int K>
__device__ __forceinline__ f32x4 gemm_ks(
    const short* __restrict__ Ah, const short* __restrict__ Al, int lda,
    const short* __restrict__ Bh, const short* __restrict__ Bl, int ldb,
    int m0, int n0, float (*lds)[32][32], int& row, int& c0) {
  const int tid = threadIdx.x;
  const int w = tid >> 6, lane = tid & 63;
  const int lm = lane & 15, kq = lane >> 4;
  constexpr int KQ = K >> 2;
  f32x4 z = {0.f, 0.f, 0.f, 0.f};
  f32x4 acc[2][2] = {{z, z}, {z, z}};
  const size_t ao = (size_t)(m0 + lm) * lda + w * KQ + kq * 8;
  const size_t bo = (size_t)(n0 + lm) * ldb + w * KQ + kq * 8;
  const size_t ao1 = ao + (size_t)16 * lda;
  const size_t bo1 = bo + (size_t)16 * ldb;
#pragma unroll 4
  for (int k = 0; k < KQ; k += 32) {
    bf16x8 ah0 = *(const bf16x8*)(Ah + ao + k);
    bf16x8 ah1 = *(const bf16x8*)(Ah + ao1 + k);
    bf16x8 bh0 = *(const bf16x8*)(Bh + bo + k);
    bf16x8 bh1 = *(const bf16x8*)(Bh + bo1 + k);
    bf16x8 al0 = *(const bf16x8*)(Al + ao + k);
    bf16x8 al1 = *(const bf16x8*)(Al + ao1 + k);
    bf16x8 bl0 = *(const bf16x8*)(Bl + bo + k);
    bf16x8 bl1 = *(const bf16x8*)(Bl + bo1 + k);
    acc[0][0] = MFMA16(ah0, bh0, acc[0][0]);
    acc[0][1] = MFMA16(ah0, bh1, acc[0][1]);
    acc[1][0] = MFMA16(ah1, bh0, acc[1][0]);
    acc[1][1] = MFMA16(ah1, bh1, acc[1][1]);
    acc[0][0] = MFMA16(ah0, bl0, acc[0][0]);
    acc[0][1] = MFMA16(ah0, bl1, acc[0][1]);
    acc[1][0] = MFMA16(ah1, bl0, acc[1][0]);
    acc[1][1] = MFMA16(ah1, bl1, acc[1][1]);
    acc[0][0] = MFMA16(al0, bh0, acc[0][0]);
    acc[0][1] = MFMA16(al0, bh1, acc[0][1]);
    acc[1][0] = MFMA16(al1, bh0, acc[1][0]);
    acc[1][1] = MFMA16(al1, bh1, acc[1][1]);
  }
#pragma unroll
  for (int i = 0; i < 2; i++)
#pragma unroll
    for (int j = 0; j < 2; j++)
#pragma unroll
      for (int e = 0; e < 4; e++)
        lds[w][i * 16 + kq * 4 + e][j * 16 + lm] = acc[i][j][e];
  __syncthreads();
  row = tid >> 3;
  c0 = (tid & 7) * 4;
  f32x4 s = *(const f32x4*)&lds[0][row][c0];
  s += *(const f32x4*)&lds[1][row][c0];
  s += *(const f32x4*)&lds[2][row][c0];
  s += *(const f32x4*)&lds[3][row][c0];
  __syncthreads();  // lds reused by next tile iteration
  return s;
}

struct P {
  const float *kin, *vin, *w1in, *w2in;
  float *w1f, *w2f, *buf1, *buf2t, *deriv, *partial;
  short *w1bth, *w1btl, *w2bh, *w2bl, *w2bth, *w2btl;
  short *Xph0, *Xpl0, *Xth0, *Xtl0, *Xph1, *Xpl1, *Xth1, *Xtl1;
  short *Ah, *Al, *Bmh, *Bml;
  short *l1h, *l1l, *l1Th, *l1Tl, *dOh, *dOl, *dOTh, *dOTl, *dpTh, *dpTl;
  short *xah, *xal, *xaTh, *xaTl;
  short *xfh, *xfl, *l1fh, *l1fl;   // xf* alias Ah/Al; l1f* alias Xpl0/Xph1
  float *out;
  unsigned *bar;  // monotonic arrival counter
};

// Grid barrier v4: arrivals via SYSTEM-scope relaxed RMW (executes at global
// coherence point); poll via SYSTEM-scope relaxed LOAD (read-through, no
// wholesale cache invalidate), every 64th poll an RMW as staleness safety
// net. One release fence (L2 wb) before arrival; one acquire fence (inv)
// after completion. Monotonic counter, guarded poll.
__device__ __forceinline__ void gsync(unsigned* bar, unsigned& tgt) {
  tgt += gridDim.x;
  __syncthreads();
  __builtin_amdgcn_fence(__ATOMIC_RELEASE, "agent");
  if (threadIdx.x == 0) {
    __hip_atomic_fetch_add(bar, 1u, __ATOMIC_RELAXED, __HIP_MEMORY_SCOPE_SYSTEM);
    int g = 0;
    for (;;) {
      unsigned v = (g & 63)
          ? __hip_atomic_load(bar, __ATOMIC_RELAXED, __HIP_MEMORY_SCOPE_SYSTEM)
          : __hip_atomic_fetch_add(bar, 0u, __ATOMIC_RELAXED,
                                   __HIP_MEMORY_SCOPE_SYSTEM);
      if (v >= tgt) break;
      __builtin_amdgcn_s_sleep(16);
      if (++g > 30000) break;  // fail as wrong numerics, not a hang
    }
  }
  __syncthreads();
  __builtin_amdgcn_fence(__ATOMIC_ACQUIRE, "agent");
}

__global__ void muon_barinit(unsigned* bar) { bar[0] = 0u; }

// deterministic per-block reduce of k2 partials -> 1/(||G||+eps) per job
__device__ __forceinline__ void norm_scales(const float* __restrict__ partial,
                                            float* snorm, float* sred) {
  const int t = threadIdx.x;
#pragma unroll
  for (int jb = 0; jb < 2; jb++) {
    float v = partial[jb * 512 + t] + partial[jb * 512 + 256 + t];
    for (int off = 32; off > 0; off >>= 1) v += __shfl_down(v, off, 64);
    if ((t & 63) == 0) sred[t >> 6] = v;
    __syncthreads();
    if (t == 0)
      snorm[jb] = 1.f / (sqrtf(sred[0] + sred[1] + sred[2] + sred[3]) + 1e-7f);
    __syncthreads();
  }
}

__device__ __forceinline__ void kx_body(const P& p, int c) {
  for (int idx = blockIdx.x * TPB2_ + threadIdx.x; idx < RACT_ * D_;
       idx += gridDim.x * TPB2_) {
    int r = idx >> 9, d = idx & 511;
    int b = r >> 4, t = r & 15;
    float v = p.kin[(size_t)(b * L_ + c * CS_ + t) * D_ + d];
    short h, l; split2(v, h, l);
    p.xah[idx] = h; p.xal[idx] = l;
    p.xaTh[(size_t)d * RACT_ + r] = h; p.xaTl[(size_t)d * RACT_ + r] = l;
  }
}

__device__ __forceinline__ void kxf_body(const P& p) {
  for (int idx = blockIdx.x * TPB2_ + threadIdx.x; idx < (int)MSZ_;
       idx += gridDim.x * TPB2_) {
    int r = idx >> 9, d = idx & 511;
    int b = r >> 6, t = r & 63;
    float v = p.kin[(size_t)(b * L_ + (NCH_ - 1) * CS_ + t) * D_ + d];
    short h, l; split2(v, h, l);
    p.xfh[idx] = h; p.xfl[idx] = l;
  }
}

__global__ __launch_bounds__(TPB2_, 2) void muon_mega(P p) {
  const int bid = blockIdx.x;
  const int tid = threadIdx.x;
  const int nb = gridDim.x;
  __shared__ float lds[4][32][32];
  __shared__ float sred[4];
  __shared__ float snorm[2];
  unsigned tgt = 0;
  short* Xph[2] = {p.Xph0, p.Xph1};
  short* Xpl[2] = {p.Xpl0, p.Xpl1};
  short* Xth[2] = {p.Xth0, p.Xth1};
  short* Xtl[2] = {p.Xtl0, p.Xtl1};

  // ---- stage: init weights/mirrors/momentum + kx(chunk 0) ----
  for (int idx = bid * TPB2_ + tid; idx < (int)MSZ_; idx += nb * TPB2_) {
    float a = p.w1in[idx], b = p.w2in[idx];
    p.w1f[idx] = a; p.w2f[idx] = b;
    p.buf1[idx] = 0.f; p.buf2t[idx] = 0.f;
    short h, l;
    int d1 = idx >> 10, h1 = idx & 1023;        // w1 [d][h]
    split2(a, h, l);
    p.w1bth[(size_t)h1 * D_ + d1] = h; p.w1btl[(size_t)h1 * D_ + d1] = l;
    int h2 = idx >> 9, d2 = idx & 511;          // w2 [h][d]
    split2(b, h, l);
    p.w2bh[idx] = h; p.w2bl[idx] = l;
    p.w2bth[(size_t)d2 * H_ + h2] = h; p.w2btl[(size_t)d2 * H_ + h2] = l;
  }
  kx_body(p, 0);
  gsync(p.bar, tgt);

  for (int c = 0; c < NCH_ - 1; c++) {
    // ---- k1a: l1 = tanh(x @ w1); 256 tiles ----
    for (int t = bid; t < 256; t += nb) {
      int m0 = (t >> 5) * 32, n0 = (t & 31) * 32;
      int row, c0;
      f32x4 s = gemm_ks<D_>(p.xah, p.xal, D_, p.w1bth, p.w1btl, D_,
                            m0, n0, lds, row, c0);
      int gm = m0 + row, gn0 = n0 + c0;
      s16x4 hv, lv; f32x4 dv;
#pragma unroll
      for (int cc = 0; cc < 4; cc++) {
        float l1v = tanhf(s[cc]);
        short h, l; split2(l1v, h, l);
        hv[cc] = h; lv[cc] = l; dv[cc] = 1.f - l1v * l1v;
        p.l1Th[(size_t)(gn0 + cc) * RACT_ + gm] = h;
        p.l1Tl[(size_t)(gn0 + cc) * RACT_ + gm] = l;
      }
      *(s16x4*)&p.l1h[(size_t)gm * H_ + gn0] = hv;
      *(s16x4*)&p.l1l[(size_t)gm * H_ + gn0] = lv;
      *(f32x4*)&p.deriv[(size_t)gm * H_ + gn0] = dv;
    }
    gsync(p.bar, tgt);

    // ---- k1b: dOut = mask*2/1024*(l1@w2 - vt); 128 tiles ----
    for (int t = bid; t < 128; t += nb) {
      int m0 = (t >> 4) * 32, n0 = (t & 15) * 32;
      int row, c0;
      f32x4 s = gemm_ks<H_>(p.l1h, p.l1l, H_, p.w2bth, p.w2btl, H_,
                            m0, n0, lds, row, c0);
      int gm = m0 + row, gn0 = n0 + c0;
      int b = gm >> 4, t15 = gm & 15;
      bool mk = (t15 <= b) && (b - t15 <= 7);
      f32x4 vt4 = {0.f, 0.f, 0.f, 0.f};
      if (mk) vt4 = *(const f32x4*)&p.vin[(size_t)(b * L_ + c * CS_ + t15) * D_ + gn0];
      s16x4 hv, lv;
#pragma unroll
      for (int cc = 0; cc < 4; cc++) {
        float dv = mk ? (2.0f / 1024.0f) * (s[cc] - vt4[cc]) : 0.f;
        short h, l; split2(dv, h, l);
        hv[cc] = h; lv[cc] = l;
        p.dOTh[(size_t)(gn0 + cc) * RACT_ + gm] = h;
        p.dOTl[(size_t)(gn0 + cc) * RACT_ + gm] = l;
      }
      *(s16x4*)&p.dOh[(size_t)gm * D_ + gn0] = hv;
      *(s16x4*)&p.dOl[(size_t)gm * D_ + gn0] = lv;
    }
    gsync(p.bar, tgt);

    // ---- k1c: dpre = (dOut @ w2^T) * deriv; 256 tiles ----
    for (int t = bid; t < 256; t += nb) {
      int m0 = (t >> 5) * 32, n0 = (t & 31) * 32;
      int row, c0;
      f32x4 s = gemm_ks<D_>(p.dOh, p.dOl, D_, p.w2bh, p.w2bl, D_,
                            m0, n0, lds, row, c0);
      int gm = m0 + row, gn0 = n0 + c0;
      f32x4 dv = *(const f32x4*)&p.deriv[(size_t)gm * H_ + gn0];
#pragma unroll
      for (int cc = 0; cc < 4; cc++) {
        float dp = s[cc] * dv[cc];
        short h, l; split2(dp, h, l);
        p.dpTh[(size_t)(gn0 + cc) * RACT_ + gm] = h;
        p.dpTl[(size_t)(gn0 + cc) * RACT_ + gm] = l;
      }
    }
    gsync(p.bar, tgt);

    // ---- k2: grads + momentum + nesterov -> split(Gn) into X0 planes ----
    for (int t = bid; t < 1024; t += nb) {
      int job = t >> 9, tt = t & 511;
      int m0 = (tt >> 5) * 32, n0 = (tt & 31) * 32;
      const short* Ah_ = job ? p.dOTh : p.xaTh;
      const short* Al_ = job ? p.dOTl : p.xaTl;
      const short* Bh_ = job ? p.l1Th : p.dpTh;
      const short* Bl_ = job ? p.l1Tl : p.dpTl;
      float* buf = job ? p.buf2t : p.buf1;
      short* xph = p.Xph0 + (size_t)job * MSZ_;
      short* xpl = p.Xpl0 + (size_t)job * MSZ_;
      short* xth = p.Xth0 + (size_t)job * MSZ_;
      short* xtl = p.Xtl0 + (size_t)job * MSZ_;
      int row, c0;
      f32x4 s = gemm_ks<RACT_>(Ah_, Al_, RACT_, Bh_, Bl_, RACT_,
                               m0, n0, lds, row, c0);
      int gm = m0 + row, gn0 = n0 + c0;
      size_t idx0 = (size_t)gm * H_ + gn0;
      f32x4 bv = *(const f32x4*)&buf[idx0];
      s16x4 hv, lv;
      float part = 0.f;
#pragma unroll
      for (int cc = 0; cc < 4; cc++) {
        float bn = MOM_ * bv[cc] + s[cc];
        bv[cc] = bn;
        float g = s[cc] + MOM_ * bn;  // nesterov (unnormalized X0)
        short h, l; split2(g, h, l);
        hv[cc] = h; lv[cc] = l;
        xth[(size_t)(gn0 + cc) * D_ + gm] = h;
        xtl[(size_t)(gn0 + cc) * D_ + gm] = l;
        part += g * g;
      }
      *(f32x4*)&buf[idx0] = bv;
      *(s16x4*)&xph[idx0] = hv;
      *(s16x4*)&xpl[idx0] = lv;
      for (int off = 32; off > 0; off >>= 1) part += __shfl_down(part, off, 64);
      if ((tid & 63) == 0) sred[tid >> 6] = part;
      __syncthreads();
      if (tid == 0) p.partial[t] = sred[0] + sred[1] + sred[2] + sred[3];
      __syncthreads();
    }
    gsync(p.bar, tgt);

    // ---- NS iterations (scale folded into it==0 epilogues) ----
    for (int it = 0; it < 5; it++) {
      int cur = it & 1, nx = cur ^ 1;
      int last = (it == 4);
      float s0v = 1.f, s1v = 1.f;
      if (it == 0) {
        norm_scales(p.partial, snorm, sred);
        s0v = snorm[0]; s1v = snorm[1];
      }
      // k4: A = X@X^T (x s^2 at it==0); 512 tiles
      for (int t = bid; t < 512; t += nb) {
        int job = t >> 8, tt = t & 255;
        int m0 = (tt >> 4) * 32, n0 = (tt & 15) * 32;
        const short* xh = Xph[cur] + (size_t)job * MSZ_;
        const short* xl = Xpl[cur] + (size_t)job * MSZ_;
        int row, c0;
        f32x4 s = gemm_ks<H_>(xh, xl, H_, xh, xl, H_, m0, n0, lds, row, c0);
        int gm = m0 + row, gn0 = n0 + c0;
        float sc = it == 0 ? (job ? s1v * s1v : s0v * s0v) : 1.f;
        short* ah = p.Ah + (size_t)job * ASZ_;
        short* al = p.Al + (size_t)job * ASZ_;
        s16x4 hv, lv;
#pragma unroll
        for (int cc = 0; cc < 4; cc++) {
          short h, l; split2(sc * s[cc], h, l);
          hv[cc] = h; lv[cc] = l;
        }
        *(s16x4*)&ah[(size_t)gm * D_ + gn0] = hv;
        *(s16x4*)&al[(size_t)gm * D_ + gn0] = lv;
      }
      gsync(p.bar, tgt);
      // k5: Bm = b*A + c*(A@A); 512 tiles
      for (int t = bid; t < 512; t += nb) {
        int job = t >> 8, tt = t & 255;
        int m0 = (tt >> 4) * 32, n0 = (tt & 15) * 32;
        const short* ah = p.Ah + (size_t)job * ASZ_;
        const short* al = p.Al + (size_t)job * ASZ_;
        int row, c0;
        f32x4 s = gemm_ks<D_>(ah, al, D_, ah, al, D_, m0, n0, lds, row, c0);
        int gm = m0 + row, gn0 = n0 + c0;
        s16x4 ahv = *(const s16x4*)&ah[(size_t)gm * D_ + gn0];
        s16x4 alv = *(const s16x4*)&al[(size_t)gm * D_ + gn0];
        short* bh = p.Bmh + (size_t)job * ASZ_;
        short* bl = p.Bml + (size_t)job * ASZ_;
        s16x4 hv, lv;
#pragma unroll
        for (int cc = 0; cc < 4; cc++) {
          float av = bs2f(ahv[cc]) + bs2f(alv[cc]);
          short h, l; split2(NSB_ * av + NSC_ * s[cc], h, l);
          hv[cc] = h; lv[cc] = l;
        }
        *(s16x4*)&bh[(size_t)gm * D_ + gn0] = hv;
        *(s16x4*)&bl[(size_t)gm * D_ + gn0] = lv;
      }
      gsync(p.bar, tgt);
      // k6: Xn = s*(a*X + Bm@X); 1024 tiles (last: weight update)
      for (int t = bid; t < 1024; t += nb) {
        int job = t >> 9, tt = t & 511;
        int m0 = (tt >> 5) * 32, n0 = (tt & 31) * 32;
        const short* bmh = p.Bmh + (size_t)job * ASZ_;
        const short* bml = p.Bml + (size_t)job * ASZ_;
        int row, c0;
        f32x4 s = gemm_ks<D_>(bmh, bml, D_, Xth[cur] + job * MSZ_,
                              Xtl[cur] + job * MSZ_, D_, m0, n0, lds, row, c0);
        int gm = m0 + row, gn0 = n0 + c0;
        size_t idx0 = (size_t)gm * H_ + gn0;
        float scl = it == 0 ? (job ? s1v : s0v) : 1.f;
        s16x4 ph = *(const s16x4*)&Xph[cur][job * MSZ_ + idx0];
        s16x4 pl = *(const s16x4*)&Xpl[cur][job * MSZ_ + idx0];
        f32x4 xv;
#pragma unroll
        for (int cc = 0; cc < 4; cc++)
          xv[cc] = scl * (NSA_ * (bs2f(ph[cc]) + bs2f(pl[cc])) + s[cc]);
        if (!last) {
          s16x4 hv, lv;
#pragma unroll
          for (int cc = 0; cc < 4; cc++) {
            short h, l; split2(xv[cc], h, l);
            hv[cc] = h; lv[cc] = l;
            Xth[nx][job * MSZ_ + (size_t)(gn0 + cc) * D_ + gm] = h;
            Xtl[nx][job * MSZ_ + (size_t)(gn0 + cc) * D_ + gm] = l;
          }
          *(s16x4*)&Xph[nx][job * MSZ_ + idx0] = hv;
          *(s16x4*)&Xpl[nx][job * MSZ_ + idx0] = lv;
        } else if (job == 0) {
          f32x4 wv = *(const f32x4*)&p.w1f[idx0];
#pragma unroll
          for (int cc = 0; cc < 4; cc++) {
            float nv = wv[cc] - LR_ * xv[cc];   // w1 [d][h] == X1 orientation
            wv[cc] = nv;
            short h, l; split2(nv, h, l);
            p.w1bth[(size_t)(gn0 + cc) * D_ + gm] = h;
            p.w1btl[(size_t)(gn0 + cc) * D_ + gm] = l;
          }
          *(f32x4*)&p.w1f[idx0] = wv;
        } else {
          s16x4 hv, lv;
#pragma unroll
          for (int cc = 0; cc < 4; cc++) {
            size_t i2 = (size_t)(gn0 + cc) * D_ + gm;  // w2 [h][d], u2 = X2^T
            float nv = p.w2f[i2] - LR_ * xv[cc];
            p.w2f[i2] = nv;
            short h, l; split2(nv, h, l);
            p.w2bh[i2] = h; p.w2bl[i2] = l;
            hv[cc] = h; lv[cc] = l;
          }
          *(s16x4*)&p.w2bth[idx0] = hv;
          *(s16x4*)&p.w2btl[idx0] = lv;
        }
      }
      if (last) {  // no dependency on k6 output: prep next chunk's x
        if (c + 1 < NCH_ - 1) kx_body(p, c + 1);
        else kxf_body(p);
      }
      gsync(p.bar, tgt);
    }
  }

  // ---- k8a: final forward layer 1; 1024 tiles ----
  for (int t = bid; t < 1024; t += nb) {
    int m0 = (t >> 5) * 32, n0 = (t & 31) * 32;
    int row, c0;
    f32x4 s = gemm_ks<D_>(p.xfh, p.xfl, D_, p.w1bth, p.w1btl, D_,
                          m0, n0, lds, row, c0);
    int gm = m0 + row, gn0 = n0 + c0;
    s16x4 hv, lv;
#pragma unroll
    for (int cc = 0; cc < 4; cc++) {
      short h, l; split2(tanhf(s[cc]), h, l);
      hv[cc] = h; lv[cc] = l;
    }
    *(s16x4*)&p.l1fh[(size_t)gm * H_ + gn0] = hv;
    *(s16x4*)&p.l1fl[(size_t)gm * H_ + gn0] = lv;
  }
  gsync(p.bar, tgt);

  // ---- k8b: final forward layer 2 -> out; 512 tiles ----
  for (int t = bid; t < 512; t += nb) {
    int m0 = (t >> 4) * 32, n0 = (t & 15) * 32;
    int row, c0;
    f32x4 s = gemm_ks<H_>(p.l1fh, p.l1fl, H_, p.w2bth, p.w2btl, H_,
                          m0, n0, lds, row, c0);
    int gm = m0 + row, gn0 = n0 + c0;
    *(f32x4*)&p.out[(size_t)gm * D_ + gn0] = s;
  }
}

extern "C" void kernel_launch(void* const* d_in, const int* in_sizes, int n_in,
                              void* d_out, int out_size, void* d_ws, size_t ws_size,
                              hipStream_t stream) {
  char* pp = (char*)d_ws;
  auto take = [&](size_t bytes) {
    char* r = pp; pp += (bytes + 255) & ~(size_t)255; return r;
  };
  const size_t L1SZ = (size_t)RACT_ * H_;
  const size_t DOSZ = (size_t)RACT_ * D_;

  P p;
  p.kin  = (const float*)d_in[0];
  p.vin  = (const float*)d_in[1];
  p.w1in = (const float*)d_in[2];
  p.w2in = (const float*)d_in[3];
  p.out  = (float*)d_out;

  p.w1f   = (float*)take(MSZ_ * 4);
  p.w2f   = (float*)take(MSZ_ * 4);
  p.buf1  = (float*)take(MSZ_ * 4);
  p.buf2t = (float*)take(MSZ_ * 4);
  p.deriv = (float*)take(L1SZ * 4);
  p.partial = (float*)take(1024 * 4);
  p.w1bth = (short*)take(MSZ_ * 2);
  p.w1btl = (short*)take(MSZ_ * 2);
  p.w2bh  = (short*)take(MSZ_ * 2);
  p.w2bl  = (short*)take(MSZ_ * 2);
  p.w2bth = (short*)take(MSZ_ * 2);
  p.w2btl = (short*)take(MSZ_ * 2);
  p.Xph0 = (short*)take(2 * MSZ_ * 2);
  p.Xpl0 = (short*)take(2 * MSZ_ * 2);
  p.Xth0 = (short*)take(2 * MSZ_ * 2);
  p.Xtl0 = (short*)take(2 * MSZ_ * 2);
  p.Xph1 = (short*)take(2 * MSZ_ * 2);
  p.Xpl1 = (short*)take(2 * MSZ_ * 2);
  p.Xth1 = (short*)take(2 * MSZ_ * 2);
  p.Xtl1 = (short*)take(2 * MSZ_ * 2);
  p.Ah  = (short*)take(2 * ASZ_ * 2);
  p.Al  = (short*)take(2 * ASZ_ * 2);
  p.Bmh = (short*)take(2 * ASZ_ * 2);
  p.Bml = (short*)take(2 * ASZ_ * 2);
  p.l1h  = (short*)take(L1SZ * 2);
  p.l1l  = (short*)take(L1SZ * 2);
  p.l1Th = (short*)take(L1SZ * 2);
  p.l1Tl = (short*)take(L1SZ * 2);
  p.dOh  = (short*)take(DOSZ * 2);
  p.dOl  = (short*)take(DOSZ * 2);
  p.dOTh = (short*)take(DOSZ * 2);
  p.dOTl = (short*)take(DOSZ * 2);
  p.dpTh = (short*)take(L1SZ * 2);
  p.dpTl = (short*)take(L1SZ * 2);
  p.xah  = (short*)take(DOSZ * 2);
  p.xal  = (short*)take(DOSZ * 2);
  p.xaTh = (short*)take(DOSZ * 2);
  p.xaTl = (short*)take(DOSZ * 2);
  p.bar  = (unsigned*)take(256);
  // final-stage aliases onto buffers dead at that point:
  // xf (1024x512) -> Ah/Al (each 2*ASZ_ == MSZ_ elements): dead after k5 it4.
  p.xfh  = p.Ah;
  p.xfl  = p.Al;
  // l1f (1024x1024 = 2*MSZ_) -> Xpl0 / Xph1: dead after chunk loop.
  p.l1fh = p.Xpl0;
  p.l1fl = p.Xph1;

  // Deterministic grid: occupancy-derived co-resident capacity, <= 512.
  int maxblk = 0;
  (void)hipOccupancyMaxActiveBlocksPerMultiprocessor(&maxblk, muon_mega,
                                                     TPB2_, 0);
  if (maxblk < 1) maxblk = 1;
  long grid = (long)maxblk * 256;
  if (grid > 512) grid = 512;

  muon_barinit<<<1, 1, 0, stream>>>(p.bar);
  void* kp[] = { &p };
  hipLaunchCooperativeKernel(muon_mega, dim3((unsigned)grid), dim3(TPB2_),
                             kp, 0, stream);
}

// Round 8
// 17003.725 us; speedup vs baseline: 6.2641x; 6.2641x over previous
//
#include <hip/hip_runtime.h>

#define D_ 512
#define H_ 1024
#define L_ 4096
#define CS_ 64
#define NCH_ 64
#define RACT_ 256
#define LR_ 0.1f
#define MOM_ 0.95f
#define NSA_ 3.4445f
#define NSB_ (-4.7750f)
#define NSC_ 2.0315f

#define MSZ_ ((size_t)D_ * H_)
#define ASZ_ ((size_t)D_ * D_)

using bf16x8 = __attribute__((ext_vector_type(8))) short;
using f32x4  = __attribute__((ext_vector_type(4))) float;
using s16x4  = __attribute__((ext_vector_type(4))) short;

__device__ __forceinline__ short f2bs(float f) {
  unsigned u = __builtin_bit_cast(unsigned, f);
  unsigned r = (u + 0x7fffu + ((u >> 16) & 1u)) >> 16;  // RNE
  return (short)r;
}
__device__ __forceinline__ float bs2f(short s) {
  unsigned u = ((unsigned)(unsigned short)s) << 16;
  return __builtin_bit_cast(float, u);
}
__device__ __forceinline__ void split2(float v, short& h, short& l) {
  h = f2bs(v);
  l = f2bs(v - bs2f(h));
}

#define MFMA16(a, b, c) __builtin_amdgcn_mfma_f32_16x16x32_bf16(a, b, c, 0, 0, 0)

// Split-bf16 NT GEMM, one 32x32 output tile per block, 4 waves split K 4 ways.
// Partials to LDS, deterministic 4-way fp32 sum. Returns 4 consecutive
// outputs per thread at (row, c0..c0+3).
template <int K>
__device__ __forceinline__ f32x4 gemm_ks(
    const short* __restrict__ Ah, const short* __restrict__ Al, int lda,
    const short* __restrict__ Bh, const short* __restrict__ Bl, int ldb,
    int m0, int n0, float (*lds)[32][32], int& row, int& c0) {
  const int tid = threadIdx.x;
  const int w = tid >> 6, lane = tid & 63;
  const int lm = lane & 15, kq = lane >> 4;
  constexpr int KQ = K >> 2;
  f32x4 z = {0.f, 0.f, 0.f, 0.f};
  f32x4 acc[2][2] = {{z, z}, {z, z}};
  const size_t ao = (size_t)(m0 + lm) * lda + w * KQ + kq * 8;
  const size_t bo = (size_t)(n0 + lm) * ldb + w * KQ + kq * 8;
  const size_t ao1 = ao + (size_t)16 * lda;
  const size_t bo1 = bo + (size_t)16 * ldb;
#pragma unroll 4
  for (int k = 0; k < KQ; k += 32) {
    bf16x8 ah0 = *(const bf16x8*)(Ah + ao + k);
    bf16x8 ah1 = *(const bf16x8*)(Ah + ao1 + k);
    bf16x8 bh0 = *(const bf16x8*)(Bh + bo + k);
    bf16x8 bh1 = *(const bf16x8*)(Bh + bo1 + k);
    bf16x8 al0 = *(const bf16x8*)(Al + ao + k);
    bf16x8 al1 = *(const bf16x8*)(Al + ao1 + k);
    bf16x8 bl0 = *(const bf16x8*)(Bl + bo + k);
    bf16x8 bl1 = *(const bf16x8*)(Bl + bo1 + k);
    acc[0][0] = MFMA16(ah0, bh0, acc[0][0]);
    acc[0][1] = MFMA16(ah0, bh1, acc[0][1]);
    acc[1][0] = MFMA16(ah1, bh0, acc[1][0]);
    acc[1][1] = MFMA16(ah1, bh1, acc[1][1]);
    acc[0][0] = MFMA16(ah0, bl0, acc[0][0]);
    acc[0][1] = MFMA16(ah0, bl1, acc[0][1]);
    acc[1][0] = MFMA16(ah1, bl0, acc[1][0]);
    acc[1][1] = MFMA16(ah1, bl1, acc[1][1]);
    acc[0][0] = MFMA16(al0, bh0, acc[0][0]);
    acc[0][1] = MFMA16(al0, bh1, acc[0][1]);
    acc[1][0] = MFMA16(al1, bh0, acc[1][0]);
    acc[1][1] = MFMA16(al1, bh1, acc[1][1]);
  }
#pragma unroll
  for (int i = 0; i < 2; i++)
#pragma unroll
    for (int j = 0; j < 2; j++)
#pragma unroll
      for (int e = 0; e < 4; e++)
        lds[w][i * 16 + kq * 4 + e][j * 16 + lm] = acc[i][j][e];
  __syncthreads();
  row = tid >> 3;
  c0 = (tid & 7) * 4;
  f32x4 s = *(const f32x4*)&lds[0][row][c0];
  s += *(const f32x4*)&lds[1][row][c0];
  s += *(const f32x4*)&lds[2][row][c0];
  s += *(const f32x4*)&lds[3][row][c0];
  return s;
}

#define GEMM_SHARED __shared__ float lds[4][32][32];

struct P {
  const float *kin, *vin, *w1in, *w2in;
  float *w1f, *w2f, *buf1, *buf2t, *deriv, *partial;
  short *w1bth, *w1btl, *w2bh, *w2bl, *w2bth, *w2btl;
  short *Xph0, *Xpl0, *Xth0, *Xtl0, *Xph1, *Xpl1, *Xth1, *Xtl1;
  short *Ah, *Al, *Bmh, *Bml;
  short *l1h, *l1l, *l1Th, *l1Tl, *dOh, *dOl, *dOTh, *dOTl, *dpTh, *dpTl;
  short *xah, *xal, *xaTh, *xaTl;
  short *xfh, *xfl, *l1fh, *l1fl;   // xf* alias Ah/Al; l1f* alias Xpl0/Xph1
  float *out;
};

// deterministic redundant reduce of k2 partials -> 1/(||G||+eps) per job
__device__ __forceinline__ void norm_scales(const float* __restrict__ partial,
                                            float* snorm, float* sred) {
  const int t = threadIdx.x;
#pragma unroll
  for (int jb = 0; jb < 2; jb++) {
    float v = partial[jb * 512 + t] + partial[jb * 512 + 256 + t];
    for (int off = 32; off > 0; off >>= 1) v += __shfl_down(v, off, 64);
    if ((t & 63) == 0) sred[t >> 6] = v;
    __syncthreads();
    if (t == 0)
      snorm[jb] = 1.f / (sqrtf(sred[0] + sred[1] + sred[2] + sred[3]) + 1e-7f);
    __syncthreads();
  }
}

// gather + split active rows (256x512) of chunk c (grid-stride)
__device__ __forceinline__ void kx_body(const P& p, int c) {
  for (int idx = blockIdx.x * blockDim.x + threadIdx.x; idx < RACT_ * D_;
       idx += gridDim.x * blockDim.x) {
    int r = idx >> 9, d = idx & 511;
    int b = r >> 4, t = r & 15;
    float v = p.kin[(size_t)(b * L_ + c * CS_ + t) * D_ + d];
    short h, l; split2(v, h, l);
    p.xah[idx] = h; p.xal[idx] = l;
    p.xaTh[(size_t)d * RACT_ + r] = h; p.xaTl[(size_t)d * RACT_ + r] = l;
  }
}

// gather + split full last chunk (1024x512) (grid-stride)
__device__ __forceinline__ void kxf_body(const P& p) {
  for (int idx = blockIdx.x * blockDim.x + threadIdx.x; idx < (int)MSZ_;
       idx += gridDim.x * blockDim.x) {
    int r = idx >> 9, d = idx & 511;
    int b = r >> 6, t = r & 63;
    float v = p.kin[(size_t)(b * L_ + (NCH_ - 1) * CS_ + t) * D_ + d];
    short h, l; split2(v, h, l);
    p.xfh[idx] = h; p.xfl[idx] = l;
  }
}

// ---------------- init: weights, split mirrors, momentum, kx(0) -------------
__global__ __launch_bounds__(256) void muon_init(P p) {
  int idx = blockIdx.x * 256 + threadIdx.x;  // grid 2048 -> MSZ_ threads
  float a = p.w1in[idx], b = p.w2in[idx];
  p.w1f[idx] = a; p.w2f[idx] = b;
  p.buf1[idx] = 0.f; p.buf2t[idx] = 0.f;
  short h, l;
  int d1 = idx >> 10, h1 = idx & 1023;        // w1 [d][h]
  split2(a, h, l);
  p.w1bth[(size_t)h1 * D_ + d1] = h; p.w1btl[(size_t)h1 * D_ + d1] = l;
  int h2 = idx >> 9, d2 = idx & 511;          // w2 [h][d]
  split2(b, h, l);
  p.w2bh[idx] = h; p.w2bl[idx] = l;
  p.w2bth[(size_t)d2 * H_ + h2] = h; p.w2btl[(size_t)d2 * H_ + h2] = l;
  if (idx < RACT_ * D_) {  // kx(0)
    int r = idx >> 9, d = idx & 511;
    int b2 = r >> 4, t = r & 15;
    float v = p.kin[(size_t)(b2 * L_ + t) * D_ + d];
    split2(v, h, l);
    p.xah[idx] = h; p.xal[idx] = l;
    p.xaTh[(size_t)d * RACT_ + r] = h; p.xaTl[(size_t)d * RACT_ + r] = l;
  }
}

// ---------------- k1a: l1 = tanh(x @ w1); grid 256 --------------------------
__global__ __launch_bounds__(256, 4) void muon_k1a(P p) {
  GEMM_SHARED
  const int m0 = (blockIdx.x >> 5) * 32, n0 = (blockIdx.x & 31) * 32;
  int row, c0;
  f32x4 s = gemm_ks<D_>(p.xah, p.xal, D_, p.w1bth, p.w1btl, D_,
                        m0, n0, lds, row, c0);
  int gm = m0 + row, gn0 = n0 + c0;
  s16x4 hv, lv; f32x4 dv;
#pragma unroll
  for (int cc = 0; cc < 4; cc++) {
    float l1v = tanhf(s[cc]);
    short h, l; split2(l1v, h, l);
    hv[cc] = h; lv[cc] = l; dv[cc] = 1.f - l1v * l1v;
    p.l1Th[(size_t)(gn0 + cc) * RACT_ + gm] = h;
    p.l1Tl[(size_t)(gn0 + cc) * RACT_ + gm] = l;
  }
  *(s16x4*)&p.l1h[(size_t)gm * H_ + gn0] = hv;
  *(s16x4*)&p.l1l[(size_t)gm * H_ + gn0] = lv;
  *(f32x4*)&p.deriv[(size_t)gm * H_ + gn0] = dv;
}

// ---------------- k1b: dOut = mask*2/1024*(l1@w2 - vt); grid 128 ------------
__global__ __launch_bounds__(256, 4) void muon_k1b(P p, int c) {
  GEMM_SHARED
  const int m0 = (blockIdx.x >> 4) * 32, n0 = (blockIdx.x & 15) * 32;
  int row, c0;
  f32x4 s = gemm_ks<H_>(p.l1h, p.l1l, H_, p.w2bth, p.w2btl, H_,
                        m0, n0, lds, row, c0);
  int gm = m0 + row, gn0 = n0 + c0;
  int b = gm >> 4, t = gm & 15;
  bool mk = (t <= b) && (b - t <= 7);
  f32x4 vt4 = {0.f, 0.f, 0.f, 0.f};
  if (mk) vt4 = *(const f32x4*)&p.vin[(size_t)(b * L_ + c * CS_ + t) * D_ + gn0];
  s16x4 hv, lv;
#pragma unroll
  for (int cc = 0; cc < 4; cc++) {
    float dv = mk ? (2.0f / 1024.0f) * (s[cc] - vt4[cc]) : 0.f;
    short h, l; split2(dv, h, l);
    hv[cc] = h; lv[cc] = l;
    p.dOTh[(size_t)(gn0 + cc) * RACT_ + gm] = h;
    p.dOTl[(size_t)(gn0 + cc) * RACT_ + gm] = l;
  }
  *(s16x4*)&p.dOh[(size_t)gm * D_ + gn0] = hv;
  *(s16x4*)&p.dOl[(size_t)gm * D_ + gn0] = lv;
}

// ---------------- k1c: dpre = (dOut @ w2^T) * deriv; grid 256 ---------------
__global__ __launch_bounds__(256, 4) void muon_k1c(P p) {
  GEMM_SHARED
  const int m0 = (blockIdx.x >> 5) * 32, n0 = (blockIdx.x & 31) * 32;
  int row, c0;
  f32x4 s = gemm_ks<D_>(p.dOh, p.dOl, D_, p.w2bh, p.w2bl, D_,
                        m0, n0, lds, row, c0);
  int gm = m0 + row, gn0 = n0 + c0;
  f32x4 dv = *(const f32x4*)&p.deriv[(size_t)gm * H_ + gn0];
#pragma unroll
  for (int cc = 0; cc < 4; cc++) {
    float dp = s[cc] * dv[cc];
    short h, l; split2(dp, h, l);
    p.dpTh[(size_t)(gn0 + cc) * RACT_ + gm] = h;
    p.dpTl[(size_t)(gn0 + cc) * RACT_ + gm] = l;
  }
}

// ---------------- k2: grads+momentum+nesterov -> split X0 planes; grid 1024 -
__global__ __launch_bounds__(256, 4) void muon_k2(P p) {
  GEMM_SHARED
  __shared__ float sred[4];
  const int bid = blockIdx.x;
  const int job = bid >> 9, tt = bid & 511;
  const int m0 = (tt >> 5) * 32, n0 = (tt & 31) * 32;
  const short* Ah_ = job ? p.dOTh : p.xaTh;
  const short* Al_ = job ? p.dOTl : p.xaTl;
  const short* Bh_ = job ? p.l1Th : p.dpTh;
  const short* Bl_ = job ? p.l1Tl : p.dpTl;
  float* buf = job ? p.buf2t : p.buf1;
  short* xph = p.Xph0 + (size_t)job * MSZ_;
  short* xpl = p.Xpl0 + (size_t)job * MSZ_;
  short* xth = p.Xth0 + (size_t)job * MSZ_;
  short* xtl = p.Xtl0 + (size_t)job * MSZ_;
  int row, c0;
  f32x4 s = gemm_ks<RACT_>(Ah_, Al_, RACT_, Bh_, Bl_, RACT_, m0, n0, lds, row, c0);
  int gm = m0 + row, gn0 = n0 + c0;
  size_t idx0 = (size_t)gm * H_ + gn0;
  f32x4 bv = *(const f32x4*)&buf[idx0];
  s16x4 hv, lv;
  float part = 0.f;
#pragma unroll
  for (int cc = 0; cc < 4; cc++) {
    float bn = MOM_ * bv[cc] + s[cc];
    bv[cc] = bn;
    float g = s[cc] + MOM_ * bn;  // nesterov (unnormalized X0)
    short h, l; split2(g, h, l);
    hv[cc] = h; lv[cc] = l;
    xth[(size_t)(gn0 + cc) * D_ + gm] = h;
    xtl[(size_t)(gn0 + cc) * D_ + gm] = l;
    part += g * g;
  }
  *(f32x4*)&buf[idx0] = bv;
  *(s16x4*)&xph[idx0] = hv;
  *(s16x4*)&xpl[idx0] = lv;
  for (int off = 32; off > 0; off >>= 1) part += __shfl_down(part, off, 64);
  if ((threadIdx.x & 63) == 0) sred[threadIdx.x >> 6] = part;
  __syncthreads();
  if (threadIdx.x == 0) p.partial[bid] = sred[0] + sred[1] + sred[2] + sred[3];
}

// ---------------- k4: A = (s^2 at it0) * X@X^T; grid 512 --------------------
__global__ __launch_bounds__(256, 4) void muon_k4(P p, int cur, int it0) {
  GEMM_SHARED
  __shared__ float sred[4];
  __shared__ float snorm[2];
  if (it0) norm_scales(p.partial, snorm, sred);
  const int bid = blockIdx.x;
  const int job = bid >> 8, tt = bid & 255;
  const int m0 = (tt >> 4) * 32, n0 = (tt & 15) * 32;
  const short* Xph_ = cur ? p.Xph1 : p.Xph0;
  const short* Xpl_ = cur ? p.Xpl1 : p.Xpl0;
  const short* xh = Xph_ + (size_t)job * MSZ_;
  const short* xl = Xpl_ + (size_t)job * MSZ_;
  int row, c0;
  f32x4 s = gemm_ks<H_>(xh, xl, H_, xh, xl, H_, m0, n0, lds, row, c0);
  int gm = m0 + row, gn0 = n0 + c0;
  float sc = it0 ? (job ? snorm[1] * snorm[1] : snorm[0] * snorm[0]) : 1.f;
  short* ah = p.Ah + (size_t)job * ASZ_;
  short* al = p.Al + (size_t)job * ASZ_;
  s16x4 hv, lv;
#pragma unroll
  for (int cc = 0; cc < 4; cc++) {
    short h, l; split2(sc * s[cc], h, l);
    hv[cc] = h; lv[cc] = l;
  }
  *(s16x4*)&ah[(size_t)gm * D_ + gn0] = hv;
  *(s16x4*)&al[(size_t)gm * D_ + gn0] = lv;
}

// ---------------- k5: Bm = b*A + c*(A@A); grid 512 --------------------------
__global__ __launch_bounds__(256, 4) void muon_k5(P p) {
  GEMM_SHARED
  const int bid = blockIdx.x;
  const int job = bid >> 8, tt = bid & 255;
  const int m0 = (tt >> 4) * 32, n0 = (tt & 15) * 32;
  const short* ah = p.Ah + (size_t)job * ASZ_;
  const short* al = p.Al + (size_t)job * ASZ_;
  int row, c0;
  f32x4 s = gemm_ks<D_>(ah, al, D_, ah, al, D_, m0, n0, lds, row, c0);  // A sym
  int gm = m0 + row, gn0 = n0 + c0;
  s16x4 ahv = *(const s16x4*)&ah[(size_t)gm * D_ + gn0];
  s16x4 alv = *(const s16x4*)&al[(size_t)gm * D_ + gn0];
  short* bh = p.Bmh + (size_t)job * ASZ_;
  short* bl = p.Bml + (size_t)job * ASZ_;
  s16x4 hv, lv;
#pragma unroll
  for (int cc = 0; cc < 4; cc++) {
    float av = bs2f(ahv[cc]) + bs2f(alv[cc]);
    short h, l; split2(NSB_ * av + NSC_ * s[cc], h, l);
    hv[cc] = h; lv[cc] = l;
  }
  *(s16x4*)&bh[(size_t)gm * D_ + gn0] = hv;
  *(s16x4*)&bl[(size_t)gm * D_ + gn0] = lv;
}

// ---------------- k6: Xn = (s at it0)*(a*X + Bm@X); grid 1024 ---------------
// last: weight update + fold next chunk's gather (kx / kxf).
__global__ __launch_bounds__(256, 4) void muon_k6(P p, int cur, int it0,
                                                  int last, int cnext) {
  GEMM_SHARED
  __shared__ float sred[4];
  __shared__ float snorm[2];
  if (it0) norm_scales(p.partial, snorm, sred);
  const int bid = blockIdx.x;
  const int job = bid >> 9, tt = bid & 511;
  const int m0 = (tt >> 5) * 32, n0 = (tt & 31) * 32;
  const short* Xph_ = cur ? p.Xph1 : p.Xph0;
  const short* Xpl_ = cur ? p.Xpl1 : p.Xpl0;
  const short* Xth_ = cur ? p.Xth1 : p.Xth0;
  const short* Xtl_ = cur ? p.Xtl1 : p.Xtl0;
  short* XphN = cur ? p.Xph0 : p.Xph1;
  short* XplN = cur ? p.Xpl0 : p.Xpl1;
  short* XthN = cur ? p.Xth0 : p.Xth1;
  short* XtlN = cur ? p.Xtl0 : p.Xtl1;
  const short* bmh = p.Bmh + (size_t)job * ASZ_;
  const short* bml = p.Bml + (size_t)job * ASZ_;
  int row, c0;
  f32x4 s = gemm_ks<D_>(bmh, bml, D_, Xth_ + job * MSZ_, Xtl_ + job * MSZ_,
                        D_, m0, n0, lds, row, c0);
  int gm = m0 + row, gn0 = n0 + c0;
  size_t idx0 = (size_t)gm * H_ + gn0;
  float scl = it0 ? (job ? snorm[1] : snorm[0]) : 1.f;
  s16x4 ph = *(const s16x4*)&Xph_[job * MSZ_ + idx0];
  s16x4 pl = *(const s16x4*)&Xpl_[job * MSZ_ + idx0];
  f32x4 xv;
#pragma unroll
  for (int cc = 0; cc < 4; cc++)
    xv[cc] = scl * (NSA_ * (bs2f(ph[cc]) + bs2f(pl[cc])) + s[cc]);
  if (!last) {
    s16x4 hv, lv;
#pragma unroll
    for (int cc = 0; cc < 4; cc++) {
      short h, l; split2(xv[cc], h, l);
      hv[cc] = h; lv[cc] = l;
      XthN[job * MSZ_ + (size_t)(gn0 + cc) * D_ + gm] = h;
      XtlN[job * MSZ_ + (size_t)(gn0 + cc) * D_ + gm] = l;
    }
    *(s16x4*)&XphN[job * MSZ_ + idx0] = hv;
    *(s16x4*)&XplN[job * MSZ_ + idx0] = lv;
  } else if (job == 0) {
    f32x4 wv = *(const f32x4*)&p.w1f[idx0];
#pragma unroll
    for (int cc = 0; cc < 4; cc++) {
      float nv = wv[cc] - LR_ * xv[cc];   // w1 [d][h] == X1 orientation
      wv[cc] = nv;
      short h, l; split2(nv, h, l);
      p.w1bth[(size_t)(gn0 + cc) * D_ + gm] = h;
      p.w1btl[(size_t)(gn0 + cc) * D_ + gm] = l;
    }
    *(f32x4*)&p.w1f[idx0] = wv;
  } else {
    s16x4 hv, lv;
#pragma unroll
    for (int cc = 0; cc < 4; cc++) {
      size_t i2 = (size_t)(gn0 + cc) * D_ + gm;  // w2 [h][d], u2 = X2^T
      float nv = p.w2f[i2] - LR_ * xv[cc];
      p.w2f[i2] = nv;
      short h, l; split2(nv, h, l);
      p.w2bh[i2] = h; p.w2bl[i2] = l;
      hv[cc] = h; lv[cc] = l;
    }
    *(s16x4*)&p.w2bth[idx0] = hv;
    *(s16x4*)&p.w2btl[idx0] = lv;
  }
  if (last) {  // gather next chunk's x (no dep on this kernel's outputs)
    if (cnext < NCH_ - 1) kx_body(p, cnext);
    else kxf_body(p);
  }
}

// ---------------- k8a: final forward layer 1; grid 1024 ---------------------
__global__ __launch_bounds__(256, 4) void muon_k8a(P p) {
  GEMM_SHARED
  const int m0 = (blockIdx.x >> 5) * 32, n0 = (blockIdx.x & 31) * 32;
  int row, c0;
  f32x4 s = gemm_ks<D_>(p.xfh, p.xfl, D_, p.w1bth, p.w1btl, D_,
                        m0, n0, lds, row, c0);
  int gm = m0 + row, gn0 = n0 + c0;
  s16x4 hv, lv;
#pragma unroll
  for (int cc = 0; cc < 4; cc++) {
    short h, l; split2(tanhf(s[cc]), h, l);
    hv[cc] = h; lv[cc] = l;
  }
  *(s16x4*)&p.l1fh[(size_t)gm * H_ + gn0] = hv;
  *(s16x4*)&p.l1fl[(size_t)gm * H_ + gn0] = lv;
}

// ---------------- k8b: final forward layer 2 -> out; grid 512 ---------------
__global__ __launch_bounds__(256, 4) void muon_k8b(P p) {
  GEMM_SHARED
  const int m0 = (blockIdx.x >> 4) * 32, n0 = (blockIdx.x & 15) * 32;
  int row, c0;
  f32x4 s = gemm_ks<H_>(p.l1fh, p.l1fl, H_, p.w2bth, p.w2btl, H_,
                        m0, n0, lds, row, c0);
  int gm = m0 + row, gn0 = n0 + c0;
  *(f32x4*)&p.out[(size_t)gm * D_ + gn0] = s;
}

extern "C" void kernel_launch(void* const* d_in, const int* in_sizes, int n_in,
                              void* d_out, int out_size, void* d_ws, size_t ws_size,
                              hipStream_t stream) {
  char* pp = (char*)d_ws;
  auto take = [&](size_t bytes) {
    char* r = pp; pp += (bytes + 255) & ~(size_t)255; return r;
  };
  const size_t L1SZ = (size_t)RACT_ * H_;
  const size_t DOSZ = (size_t)RACT_ * D_;

  P p;
  p.kin  = (const float*)d_in[0];
  p.vin  = (const float*)d_in[1];
  p.w1in = (const float*)d_in[2];
  p.w2in = (const float*)d_in[3];
  p.out  = (float*)d_out;

  p.w1f   = (float*)take(MSZ_ * 4);
  p.w2f   = (float*)take(MSZ_ * 4);
  p.buf1  = (float*)take(MSZ_ * 4);
  p.buf2t = (float*)take(MSZ_ * 4);
  p.deriv = (float*)take(L1SZ * 4);
  p.partial = (float*)take(1024 * 4);
  p.w1bth = (short*)take(MSZ_ * 2);
  p.w1btl = (short*)take(MSZ_ * 2);
  p.w2bh  = (short*)take(MSZ_ * 2);
  p.w2bl  = (short*)take(MSZ_ * 2);
  p.w2bth = (short*)take(MSZ_ * 2);
  p.w2btl = (short*)take(MSZ_ * 2);
  p.Xph0 = (short*)take(2 * MSZ_ * 2);
  p.Xpl0 = (short*)take(2 * MSZ_ * 2);
  p.Xth0 = (short*)take(2 * MSZ_ * 2);
  p.Xtl0 = (short*)take(2 * MSZ_ * 2);
  p.Xph1 = (short*)take(2 * MSZ_ * 2);
  p.Xpl1 = (short*)take(2 * MSZ_ * 2);
  p.Xth1 = (short*)take(2 * MSZ_ * 2);
  p.Xtl1 = (short*)take(2 * MSZ_ * 2);
  p.Ah  = (short*)take(2 * ASZ_ * 2);
  p.Al  = (short*)take(2 * ASZ_ * 2);
  p.Bmh = (short*)take(2 * ASZ_ * 2);
  p.Bml = (short*)take(2 * ASZ_ * 2);
  p.l1h  = (short*)take(L1SZ * 2);
  p.l1l  = (short*)take(L1SZ * 2);
  p.l1Th = (short*)take(L1SZ * 2);
  p.l1Tl = (short*)take(L1SZ * 2);
  p.dOh  = (short*)take(DOSZ * 2);
  p.dOl  = (short*)take(DOSZ * 2);
  p.dOTh = (short*)take(DOSZ * 2);
  p.dOTl = (short*)take(DOSZ * 2);
  p.dpTh = (short*)take(L1SZ * 2);
  p.dpTl = (short*)take(L1SZ * 2);
  p.xah  = (short*)take(DOSZ * 2);
  p.xal  = (short*)take(DOSZ * 2);
  p.xaTh = (short*)take(DOSZ * 2);
  p.xaTl = (short*)take(DOSZ * 2);
  // final-stage aliases onto buffers dead at that point:
  // xf (1024x512 = MSZ_ elems) -> Ah/Al (2*ASZ_ == MSZ_ elems each): A is
  // dead after k5 of the last NS iter; k6-last reads only Bm/Xt/Xp.
  p.xfh  = p.Ah;
  p.xfl  = p.Al;
  // l1f (1024x1024 = 2*MSZ_ elems) -> Xpl0 / Xph1: dead after chunk loop
  // (k8a, which writes them, runs after the kernel boundary).
  p.l1fh = p.Xpl0;
  p.l1fl = p.Xph1;

  muon_init<<<2048, 256, 0, stream>>>(p);
  for (int c = 0; c < NCH_ - 1; c++) {
    muon_k1a<<<256, 256, 0, stream>>>(p);
    muon_k1b<<<128, 256, 0, stream>>>(p, c);
    muon_k1c<<<256, 256, 0, stream>>>(p);
    muon_k2<<<1024, 256, 0, stream>>>(p);
    for (int it = 0; it < 5; it++) {
      int cur = it & 1;
      muon_k4<<<512, 256, 0, stream>>>(p, cur, it == 0 ? 1 : 0);
      muon_k5<<<512, 256, 0, stream>>>(p);
      muon_k6<<<1024, 256, 0, stream>>>(p, cur, it == 0 ? 1 : 0,
                                        it == 4 ? 1 : 0, c + 1);
    }
  }
  muon_k8a<<<1024, 256, 0, stream>>>(p);
  muon_k8b<<<512, 256, 0, stream>>>(p);
}

// Round 9
// 16969.836 us; speedup vs baseline: 6.2766x; 1.0020x over previous
//
#include <hip/hip_runtime.h>

#define D_ 512
#define H_ 1024
#define L_ 4096
#define CS_ 64
#define NCH_ 64
#define RACT_ 256
#define LR_ 0.1f
#define MOM_ 0.95f
#define NSA_ 3.4445f
#define NSB_ (-4.7750f)
#define NSC_ 2.0315f

#define MSZ_ ((size_t)D_ * H_)
#define ASZ_ ((size_t)D_ * D_)

using bf16x8 = __attribute__((ext_vector_type(8))) short;
using f32x4  = __attribute__((ext_vector_type(4))) float;
using s16x4  = __attribute__((ext_vector_type(4))) short;

__device__ __forceinline__ short f2bs(float f) {
  unsigned u = __builtin_bit_cast(unsigned, f);
  unsigned r = (u + 0x7fffu + ((u >> 16) & 1u)) >> 16;  // RNE
  return (short)r;
}
__device__ __forceinline__ float bs2f(short s) {
  unsigned u = ((unsigned)(unsigned short)s) << 16;
  return __builtin_bit_cast(float, u);
}
__device__ __forceinline__ void split2(float v, short& h, short& l) {
  h = f2bs(v);
  l = f2bs(v - bs2f(h));
}

#define MFMA16(a, b, c) __builtin_amdgcn_mfma_f32_16x16x32_bf16(a, b, c, 0, 0, 0)

// Split-bf16 NT GEMM, one 32x32 output tile per block, 4 waves split K 4 ways.
// Partials to LDS, deterministic 4-way fp32 sum. Returns 4 consecutive
// outputs per thread at (row, c0..c0+3).
template <int K>
__device__ __forceinline__ f32x4 gemm_ks(
    const short* __restrict__ Ah, const short* __restrict__ Al, int lda,
    const short* __restrict__ Bh, const short* __restrict__ Bl, int ldb,
    int m0, int n0, float (*lds)[32][32], int& row, int& c0) {
  const int tid = threadIdx.x;
  const int w = tid >> 6, lane = tid & 63;
  const int lm = lane & 15, kq = lane >> 4;
  constexpr int KQ = K >> 2;
  f32x4 z = {0.f, 0.f, 0.f, 0.f};
  f32x4 acc[2][2] = {{z, z}, {z, z}};
  const size_t ao = (size_t)(m0 + lm) * lda + w * KQ + kq * 8;
  const size_t bo = (size_t)(n0 + lm) * ldb + w * KQ + kq * 8;
  const size_t ao1 = ao + (size_t)16 * lda;
  const size_t bo1 = bo + (size_t)16 * ldb;
#pragma unroll 4
  for (int k = 0; k < KQ; k += 32) {
    bf16x8 ah0 = *(const bf16x8*)(Ah + ao + k);
    bf16x8 ah1 = *(const bf16x8*)(Ah + ao1 + k);
    bf16x8 bh0 = *(const bf16x8*)(Bh + bo + k);
    bf16x8 bh1 = *(const bf16x8*)(Bh + bo1 + k);
    bf16x8 al0 = *(const bf16x8*)(Al + ao + k);
    bf16x8 al1 = *(const bf16x8*)(Al + ao1 + k);
    bf16x8 bl0 = *(const bf16x8*)(Bl + bo + k);
    bf16x8 bl1 = *(const bf16x8*)(Bl + bo1 + k);
    acc[0][0] = MFMA16(ah0, bh0, acc[0][0]);
    acc[0][1] = MFMA16(ah0, bh1, acc[0][1]);
    acc[1][0] = MFMA16(ah1, bh0, acc[1][0]);
    acc[1][1] = MFMA16(ah1, bh1, acc[1][1]);
    acc[0][0] = MFMA16(ah0, bl0, acc[0][0]);
    acc[0][1] = MFMA16(ah0, bl1, acc[0][1]);
    acc[1][0] = MFMA16(ah1, bl0, acc[1][0]);
    acc[1][1] = MFMA16(ah1, bl1, acc[1][1]);
    acc[0][0] = MFMA16(al0, bh0, acc[0][0]);
    acc[0][1] = MFMA16(al0, bh1, acc[0][1]);
    acc[1][0] = MFMA16(al1, bh0, acc[1][0]);
    acc[1][1] = MFMA16(al1, bh1, acc[1][1]);
  }
#pragma unroll
  for (int i = 0; i < 2; i++)
#pragma unroll
    for (int j = 0; j < 2; j++)
#pragma unroll
      for (int e = 0; e < 4; e++)
        lds[w][i * 16 + kq * 4 + e][j * 16 + lm] = acc[i][j][e];
  __syncthreads();
  row = tid >> 3;
  c0 = (tid & 7) * 4;
  f32x4 s = *(const f32x4*)&lds[0][row][c0];
  s += *(const f32x4*)&lds[1][row][c0];
  s += *(const f32x4*)&lds[2][row][c0];
  s += *(const f32x4*)&lds[3][row][c0];
  return s;
}

#define GEMM_SHARED __shared__ float lds[4][32][32];

// Coalesced transposed store of a 32x32 split-bf16 tile: stage in LDS
// (reusing the gemm scratch), re-read transposed, emit 8B contiguous stores.
// Writes th/tl[(n0+r)*ldt + m0+c] = value(gm=m0+c, gn=n0+r).
__device__ __forceinline__ void store_T(
    void* ldsraw, int row, int c0, const s16x4& hv, const s16x4& lv,
    short* __restrict__ th, short* __restrict__ tl, int ldt, int m0, int n0) {
  short (*sh)[36] = (short(*)[36])ldsraw;
  short (*sl)[36] = (short(*)[36])ldsraw + 32;
  __syncthreads();  // all partial-sum reads of lds are done
#pragma unroll
  for (int cc = 0; cc < 4; cc++) {
    sh[row][c0 + cc] = hv[cc];
    sl[row][c0 + cc] = lv[cc];
  }
  __syncthreads();
  const int tr = threadIdx.x >> 3;
  const int tc = (threadIdx.x & 7) * 4;
  s16x4 oh, ol;
#pragma unroll
  for (int j = 0; j < 4; j++) { oh[j] = sh[tc + j][tr]; ol[j] = sl[tc + j][tr]; }
  *(s16x4*)&th[(size_t)(n0 + tr) * ldt + m0 + tc] = oh;
  *(s16x4*)&tl[(size_t)(n0 + tr) * ldt + m0 + tc] = ol;
}

struct P {
  const float *kin, *vin, *w1in, *w2in;
  float *w1f, *w2f /* stored TRANSPOSED: [d][h] */, *buf1, *buf2t, *deriv, *partial;
  short *w1bth, *w1btl, *w2bh, *w2bl, *w2bth, *w2btl;
  short *Xph0, *Xpl0, *Xth0, *Xtl0, *Xph1, *Xpl1, *Xth1, *Xtl1;
  short *Ah, *Al, *Bmh, *Bml;
  short *l1h, *l1l, *l1Th, *l1Tl, *dOh, *dOl, *dOTh, *dOTl, *dpTh, *dpTl;
  short *xah, *xal, *xaTh, *xaTl;
  short *xfh, *xfl, *l1fh, *l1fl;   // xf* alias Ah/Al; l1f* alias Xpl0/Xph1
  float *out;
};

// deterministic redundant reduce of k2 partials -> 1/(||G||+eps) per job
__device__ __forceinline__ void norm_scales(const float* __restrict__ partial,
                                            float* snorm, float* sred) {
  const int t = threadIdx.x;
#pragma unroll
  for (int jb = 0; jb < 2; jb++) {
    float v = partial[jb * 512 + t] + partial[jb * 512 + 256 + t];
    for (int off = 32; off > 0; off >>= 1) v += __shfl_down(v, off, 64);
    if ((t & 63) == 0) sred[t >> 6] = v;
    __syncthreads();
    if (t == 0)
      snorm[jb] = 1.f / (sqrtf(sred[0] + sred[1] + sred[2] + sred[3]) + 1e-7f);
    __syncthreads();
  }
}

// gather + split active rows (256x512) of chunk c (grid-stride)
__device__ __forceinline__ void kx_body(const P& p, int c) {
  for (int idx = blockIdx.x * blockDim.x + threadIdx.x; idx < RACT_ * D_;
       idx += gridDim.x * blockDim.x) {
    int r = idx >> 9, d = idx & 511;
    int b = r >> 4, t = r & 15;
    float v = p.kin[(size_t)(b * L_ + c * CS_ + t) * D_ + d];
    short h, l; split2(v, h, l);
    p.xah[idx] = h; p.xal[idx] = l;
    p.xaTh[(size_t)d * RACT_ + r] = h; p.xaTl[(size_t)d * RACT_ + r] = l;
  }
}

// gather + split full last chunk (1024x512) (grid-stride)
__device__ __forceinline__ void kxf_body(const P& p) {
  for (int idx = blockIdx.x * blockDim.x + threadIdx.x; idx < (int)MSZ_;
       idx += gridDim.x * blockDim.x) {
    int r = idx >> 9, d = idx & 511;
    int b = r >> 6, t = r & 63;
    float v = p.kin[(size_t)(b * L_ + (NCH_ - 1) * CS_ + t) * D_ + d];
    short h, l; split2(v, h, l);
    p.xfh[idx] = h; p.xfl[idx] = l;
  }
}

// ---------------- init: weights, split mirrors, momentum, kx(0) -------------
__global__ __launch_bounds__(256) void muon_init(P p) {
  int idx = blockIdx.x * 256 + threadIdx.x;  // grid 2048 -> MSZ_ threads
  float a = p.w1in[idx], b = p.w2in[idx];
  p.w1f[idx] = a;
  p.buf1[idx] = 0.f; p.buf2t[idx] = 0.f;
  short h, l;
  int d1 = idx >> 10, h1 = idx & 1023;        // w1 [d][h]
  split2(a, h, l);
  p.w1bth[(size_t)h1 * D_ + d1] = h; p.w1btl[(size_t)h1 * D_ + d1] = l;
  int h2 = idx >> 9, d2 = idx & 511;          // w2 input [h][d]
  p.w2f[(size_t)d2 * H_ + h2] = b;            // w2f stored transposed [d][h]
  split2(b, h, l);
  p.w2bh[idx] = h; p.w2bl[idx] = l;
  p.w2bth[(size_t)d2 * H_ + h2] = h; p.w2btl[(size_t)d2 * H_ + h2] = l;
  if (idx < RACT_ * D_) {  // kx(0)
    int r = idx >> 9, d = idx & 511;
    int b2 = r >> 4, t = r & 15;
    float v = p.kin[(size_t)(b2 * L_ + t) * D_ + d];
    split2(v, h, l);
    p.xah[idx] = h; p.xal[idx] = l;
    p.xaTh[(size_t)d * RACT_ + r] = h; p.xaTl[(size_t)d * RACT_ + r] = l;
  }
}

// ---------------- k1a: l1 = tanh(x @ w1); grid 256 --------------------------
__global__ __launch_bounds__(256, 4) void muon_k1a(P p) {
  GEMM_SHARED
  const int m0 = (blockIdx.x >> 5) * 32, n0 = (blockIdx.x & 31) * 32;
  int row, c0;
  f32x4 s = gemm_ks<D_>(p.xah, p.xal, D_, p.w1bth, p.w1btl, D_,
                        m0, n0, lds, row, c0);
  int gm = m0 + row, gn0 = n0 + c0;
  s16x4 hv, lv; f32x4 dv;
#pragma unroll
  for (int cc = 0; cc < 4; cc++) {
    float l1v = tanhf(s[cc]);
    short h, l; split2(l1v, h, l);
    hv[cc] = h; lv[cc] = l; dv[cc] = 1.f - l1v * l1v;
  }
  *(s16x4*)&p.l1h[(size_t)gm * H_ + gn0] = hv;
  *(s16x4*)&p.l1l[(size_t)gm * H_ + gn0] = lv;
  *(f32x4*)&p.deriv[(size_t)gm * H_ + gn0] = dv;
  store_T(lds, row, c0, hv, lv, p.l1Th, p.l1Tl, RACT_, m0, n0);
}

// ---------------- k1b: dOut = mask*2/1024*(l1@w2 - vt); grid 128 ------------
__global__ __launch_bounds__(256, 4) void muon_k1b(P p, int c) {
  GEMM_SHARED
  const int m0 = (blockIdx.x >> 4) * 32, n0 = (blockIdx.x & 15) * 32;
  int row, c0;
  f32x4 s = gemm_ks<H_>(p.l1h, p.l1l, H_, p.w2bth, p.w2btl, H_,
                        m0, n0, lds, row, c0);
  int gm = m0 + row, gn0 = n0 + c0;
  int b = gm >> 4, t = gm & 15;
  bool mk = (t <= b) && (b - t <= 7);
  f32x4 vt4 = {0.f, 0.f, 0.f, 0.f};
  if (mk) vt4 = *(const f32x4*)&p.vin[(size_t)(b * L_ + c * CS_ + t) * D_ + gn0];
  s16x4 hv, lv;
#pragma unroll
  for (int cc = 0; cc < 4; cc++) {
    float dv = mk ? (2.0f / 1024.0f) * (s[cc] - vt4[cc]) : 0.f;
    short h, l; split2(dv, h, l);
    hv[cc] = h; lv[cc] = l;
  }
  *(s16x4*)&p.dOh[(size_t)gm * D_ + gn0] = hv;
  *(s16x4*)&p.dOl[(size_t)gm * D_ + gn0] = lv;
  store_T(lds, row, c0, hv, lv, p.dOTh, p.dOTl, RACT_, m0, n0);
}

// ---------------- k1c: dpre = (dOut @ w2^T) * deriv; grid 256 ---------------
__global__ __launch_bounds__(256, 4) void muon_k1c(P p) {
  GEMM_SHARED
  const int m0 = (blockIdx.x >> 5) * 32, n0 = (blockIdx.x & 31) * 32;
  int row, c0;
  f32x4 s = gemm_ks<D_>(p.dOh, p.dOl, D_, p.w2bh, p.w2bl, D_,
                        m0, n0, lds, row, c0);
  int gm = m0 + row, gn0 = n0 + c0;
  f32x4 dv = *(const f32x4*)&p.deriv[(size_t)gm * H_ + gn0];
  s16x4 hv, lv;
#pragma unroll
  for (int cc = 0; cc < 4; cc++) {
    float dp = s[cc] * dv[cc];
    short h, l; split2(dp, h, l);
    hv[cc] = h; lv[cc] = l;
  }
  store_T(lds, row, c0, hv, lv, p.dpTh, p.dpTl, RACT_, m0, n0);
}

// ---------------- k2: grads+momentum+nesterov -> split X0 planes; grid 1024 -
__global__ __launch_bounds__(256, 4) void muon_k2(P p) {
  GEMM_SHARED
  __shared__ float sred[4];
  const int bid = blockIdx.x;
  const int job = bid >> 9, tt = bid & 511;
  const int m0 = (tt >> 5) * 32, n0 = (tt & 31) * 32;
  const short* Ah_ = job ? p.dOTh : p.xaTh;
  const short* Al_ = job ? p.dOTl : p.xaTl;
  const short* Bh_ = job ? p.l1Th : p.dpTh;
  const short* Bl_ = job ? p.l1Tl : p.dpTl;
  float* buf = job ? p.buf2t : p.buf1;
  short* xph = p.Xph0 + (size_t)job * MSZ_;
  short* xpl = p.Xpl0 + (size_t)job * MSZ_;
  int row, c0;
  f32x4 s = gemm_ks<RACT_>(Ah_, Al_, RACT_, Bh_, Bl_, RACT_, m0, n0, lds, row, c0);
  int gm = m0 + row, gn0 = n0 + c0;
  size_t idx0 = (size_t)gm * H_ + gn0;
  f32x4 bv = *(const f32x4*)&buf[idx0];
  s16x4 hv, lv;
  float part = 0.f;
#pragma unroll
  for (int cc = 0; cc < 4; cc++) {
    float bn = MOM_ * bv[cc] + s[cc];
    bv[cc] = bn;
    float g = s[cc] + MOM_ * bn;  // nesterov (unnormalized X0)
    short h, l; split2(g, h, l);
    hv[cc] = h; lv[cc] = l;
    part += g * g;
  }
  *(f32x4*)&buf[idx0] = bv;
  *(s16x4*)&xph[idx0] = hv;
  *(s16x4*)&xpl[idx0] = lv;
  store_T(lds, row, c0, hv, lv, p.Xth0 + (size_t)job * MSZ_,
          p.Xtl0 + (size_t)job * MSZ_, D_, m0, n0);
  for (int off = 32; off > 0; off >>= 1) part += __shfl_down(part, off, 64);
  if ((threadIdx.x & 63) == 0) sred[threadIdx.x >> 6] = part;
  __syncthreads();
  if (threadIdx.x == 0) p.partial[bid] = sred[0] + sred[1] + sred[2] + sred[3];
}

// ---------------- k4: A = (s^2 at it0) * X@X^T; grid 272 (triangular) -------
__global__ __launch_bounds__(256, 4) void muon_k4(P p, int cur, int it0) {
  GEMM_SHARED
  __shared__ float sred[4];
  __shared__ float snorm[2];
  if (it0) norm_scales(p.partial, snorm, sred);
  const int bid = blockIdx.x;            // 2 jobs x 136 lower-tri tiles
  const int job = bid >= 136;
  int tt = job ? bid - 136 : bid;
  int mt = 0;
  while (tt >= 16 - mt) { tt -= 16 - mt; mt++; }
  const int nt = mt + tt;
  const int m0 = mt * 32, n0 = nt * 32;
  const short* Xph_ = cur ? p.Xph1 : p.Xph0;
  const short* Xpl_ = cur ? p.Xpl1 : p.Xpl0;
  const short* xh = Xph_ + (size_t)job * MSZ_;
  const short* xl = Xpl_ + (size_t)job * MSZ_;
  int row, c0;
  f32x4 s = gemm_ks<H_>(xh, xl, H_, xh, xl, H_, m0, n0, lds, row, c0);
  int gm = m0 + row, gn0 = n0 + c0;
  float sc = it0 ? (job ? snorm[1] * snorm[1] : snorm[0] * snorm[0]) : 1.f;
  short* ah = p.Ah + (size_t)job * ASZ_;
  short* al = p.Al + (size_t)job * ASZ_;
  s16x4 hv, lv;
#pragma unroll
  for (int cc = 0; cc < 4; cc++) {
    short h, l; split2(sc * s[cc], h, l);
    hv[cc] = h; lv[cc] = l;
  }
  *(s16x4*)&ah[(size_t)gm * D_ + gn0] = hv;
  *(s16x4*)&al[(size_t)gm * D_ + gn0] = lv;
  if (mt != nt) store_T(lds, row, c0, hv, lv, ah, al, D_, m0, n0);  // mirror
}

// ---------------- k5: Bm = b*A + c*(A@A); grid 272 (triangular) -------------
__global__ __launch_bounds__(256, 4) void muon_k5(P p) {
  GEMM_SHARED
  const int bid = blockIdx.x;
  const int job = bid >= 136;
  int tt = job ? bid - 136 : bid;
  int mt = 0;
  while (tt >= 16 - mt) { tt -= 16 - mt; mt++; }
  const int nt = mt + tt;
  const int m0 = mt * 32, n0 = nt * 32;
  const short* ah = p.Ah + (size_t)job * ASZ_;
  const short* al = p.Al + (size_t)job * ASZ_;
  int row, c0;
  f32x4 s = gemm_ks<D_>(ah, al, D_, ah, al, D_, m0, n0, lds, row, c0);  // A sym
  int gm = m0 + row, gn0 = n0 + c0;
  s16x4 ahv = *(const s16x4*)&ah[(size_t)gm * D_ + gn0];
  s16x4 alv = *(const s16x4*)&al[(size_t)gm * D_ + gn0];
  short* bh = p.Bmh + (size_t)job * ASZ_;
  short* bl = p.Bml + (size_t)job * ASZ_;
  s16x4 hv, lv;
#pragma unroll
  for (int cc = 0; cc < 4; cc++) {
    float av = bs2f(ahv[cc]) + bs2f(alv[cc]);
    short h, l; split2(NSB_ * av + NSC_ * s[cc], h, l);
    hv[cc] = h; lv[cc] = l;
  }
  *(s16x4*)&bh[(size_t)gm * D_ + gn0] = hv;
  *(s16x4*)&bl[(size_t)gm * D_ + gn0] = lv;
  if (mt != nt) store_T(lds, row, c0, hv, lv, bh, bl, D_, m0, n0);  // mirror
}

// ---------------- k6: Xn = (s at it0)*(a*X + Bm@X); grid 1024 ---------------
// last: weight update + fold next chunk's gather (kx / kxf).
__global__ __launch_bounds__(256, 4) void muon_k6(P p, int cur, int it0,
                                                  int last, int cnext) {
  GEMM_SHARED
  __shared__ float sred[4];
  __shared__ float snorm[2];
  if (it0) norm_scales(p.partial, snorm, sred);
  const int bid = blockIdx.x;
  const int job = bid >> 9, tt = bid & 511;
  const int m0 = (tt >> 5) * 32, n0 = (tt & 31) * 32;
  const short* Xph_ = cur ? p.Xph1 : p.Xph0;
  const short* Xpl_ = cur ? p.Xpl1 : p.Xpl0;
  const short* Xth_ = cur ? p.Xth1 : p.Xth0;
  const short* Xtl_ = cur ? p.Xtl1 : p.Xtl0;
  short* XphN = cur ? p.Xph0 : p.Xph1;
  short* XplN = cur ? p.Xpl0 : p.Xpl1;
  short* XthN = cur ? p.Xth0 : p.Xth1;
  short* XtlN = cur ? p.Xtl0 : p.Xtl1;
  const short* bmh = p.Bmh + (size_t)job * ASZ_;
  const short* bml = p.Bml + (size_t)job * ASZ_;
  int row, c0;
  f32x4 s = gemm_ks<D_>(bmh, bml, D_, Xth_ + job * MSZ_, Xtl_ + job * MSZ_,
                        D_, m0, n0, lds, row, c0);
  int gm = m0 + row, gn0 = n0 + c0;
  size_t idx0 = (size_t)gm * H_ + gn0;
  float scl = it0 ? (job ? snorm[1] : snorm[0]) : 1.f;
  s16x4 ph = *(const s16x4*)&Xph_[job * MSZ_ + idx0];
  s16x4 pl = *(const s16x4*)&Xpl_[job * MSZ_ + idx0];
  f32x4 xv;
#pragma unroll
  for (int cc = 0; cc < 4; cc++)
    xv[cc] = scl * (NSA_ * (bs2f(ph[cc]) + bs2f(pl[cc])) + s[cc]);
  if (!last) {
    s16x4 hv, lv;
#pragma unroll
    for (int cc = 0; cc < 4; cc++) {
      short h, l; split2(xv[cc], h, l);
      hv[cc] = h; lv[cc] = l;
    }
    *(s16x4*)&XphN[job * MSZ_ + idx0] = hv;
    *(s16x4*)&XplN[job * MSZ_ + idx0] = lv;
    store_T(lds, row, c0, hv, lv, XthN + job * MSZ_, XtlN + job * MSZ_,
            D_, m0, n0);
  } else if (job == 0) {
    f32x4 wv = *(const f32x4*)&p.w1f[idx0];
    s16x4 hv, lv;
#pragma unroll
    for (int cc = 0; cc < 4; cc++) {
      float nv = wv[cc] - LR_ * xv[cc];   // w1 [d][h] == X1 orientation
      wv[cc] = nv;
      short h, l; split2(nv, h, l);
      hv[cc] = h; lv[cc] = l;
    }
    *(f32x4*)&p.w1f[idx0] = wv;
    store_T(lds, row, c0, hv, lv, p.w1bth, p.w1btl, D_, m0, n0);
  } else {
    // w2f stored transposed [d][h]: contiguous at idx0. u2 = X2^T.
    f32x4 wv = *(const f32x4*)&p.w2f[idx0];
    s16x4 hv, lv;
#pragma unroll
    for (int cc = 0; cc < 4; cc++) {
      float nv = wv[cc] - LR_ * xv[cc];
      wv[cc] = nv;
      short h, l; split2(nv, h, l);
      hv[cc] = h; lv[cc] = l;
    }
    *(f32x4*)&p.w2f[idx0] = wv;
    *(s16x4*)&p.w2bth[idx0] = hv;
    *(s16x4*)&p.w2btl[idx0] = lv;
    store_T(lds, row, c0, hv, lv, p.w2bh, p.w2bl, D_, m0, n0);
  }
  if (last) {  // gather next chunk's x (no dep on this kernel's outputs)
    if (cnext < NCH_ - 1) kx_body(p, cnext);
    else kxf_body(p);
  }
}

// ---------------- k8a: final forward layer 1; grid 1024 ---------------------
__global__ __launch_bounds__(256, 4) void muon_k8a(P p) {
  GEMM_SHARED
  const int m0 = (blockIdx.x >> 5) * 32, n0 = (blockIdx.x & 31) * 32;
  int row, c0;
  f32x4 s = gemm_ks<D_>(p.xfh, p.xfl, D_, p.w1bth, p.w1btl, D_,
                        m0, n0, lds, row, c0);
  int gm = m0 + row, gn0 = n0 + c0;
  s16x4 hv, lv;
#pragma unroll
  for (int cc = 0; cc < 4; cc++) {
    short h, l; split2(tanhf(s[cc]), h, l);
    hv[cc] = h; lv[cc] = l;
  }
  *(s16x4*)&p.l1fh[(size_t)gm * H_ + gn0] = hv;
  *(s16x4*)&p.l1fl[(size_t)gm * H_ + gn0] = lv;
}

// ---------------- k8b: final forward layer 2 -> out; grid 512 ---------------
__global__ __launch_bounds__(256, 4) void muon_k8b(P p) {
  GEMM_SHARED
  const int m0 = (blockIdx.x >> 4) * 32, n0 = (blockIdx.x & 15) * 32;
  int row, c0;
  f32x4 s = gemm_ks<H_>(p.l1fh, p.l1fl, H_, p.w2bth, p.w2btl, H_,
                        m0, n0, lds, row, c0);
  int gm = m0 + row, gn0 = n0 + c0;
  *(f32x4*)&p.out[(size_t)gm * D_ + gn0] = s;
}

extern "C" void kernel_launch(void* const* d_in, const int* in_sizes, int n_in,
                              void* d_out, int out_size, void* d_ws, size_t ws_size,
                              hipStream_t stream) {
  char* pp = (char*)d_ws;
  auto take = [&](size_t bytes) {
    char* r = pp; pp += (bytes + 255) & ~(size_t)255; return r;
  };
  const size_t L1SZ = (size_t)RACT_ * H_;
  const size_t DOSZ = (size_t)RACT_ * D_;

  P p;
  p.kin  = (const float*)d_in[0];
  p.vin  = (const float*)d_in[1];
  p.w1in = (const float*)d_in[2];
  p.w2in = (const float*)d_in[3];
  p.out  = (float*)d_out;

  p.w1f   = (float*)take(MSZ_ * 4);
  p.w2f   = (float*)take(MSZ_ * 4);
  p.buf1  = (float*)take(MSZ_ * 4);
  p.buf2t = (float*)take(MSZ_ * 4);
  p.deriv = (float*)take(L1SZ * 4);
  p.partial = (float*)take(1024 * 4);
  p.w1bth = (short*)take(MSZ_ * 2);
  p.w1btl = (short*)take(MSZ_ * 2);
  p.w2bh  = (short*)take(MSZ_ * 2);
  p.w2bl  = (short*)take(MSZ_ * 2);
  p.w2bth = (short*)take(MSZ_ * 2);
  p.w2btl = (short*)take(MSZ_ * 2);
  p.Xph0 = (short*)take(2 * MSZ_ * 2);
  p.Xpl0 = (short*)take(2 * MSZ_ * 2);
  p.Xth0 = (short*)take(2 * MSZ_ * 2);
  p.Xtl0 = (short*)take(2 * MSZ_ * 2);
  p.Xph1 = (short*)take(2 * MSZ_ * 2);
  p.Xpl1 = (short*)take(2 * MSZ_ * 2);
  p.Xth1 = (short*)take(2 * MSZ_ * 2);
  p.Xtl1 = (short*)take(2 * MSZ_ * 2);
  p.Ah  = (short*)take(2 * ASZ_ * 2);
  p.Al  = (short*)take(2 * ASZ_ * 2);
  p.Bmh = (short*)take(2 * ASZ_ * 2);
  p.Bml = (short*)take(2 * ASZ_ * 2);
  p.l1h  = (short*)take(L1SZ * 2);
  p.l1l  = (short*)take(L1SZ * 2);
  p.l1Th = (short*)take(L1SZ * 2);
  p.l1Tl = (short*)take(L1SZ * 2);
  p.dOh  = (short*)take(DOSZ * 2);
  p.dOl  = (short*)take(DOSZ * 2);
  p.dOTh = (short*)take(DOSZ * 2);
  p.dOTl = (short*)take(DOSZ * 2);
  p.dpTh = (short*)take(L1SZ * 2);
  p.dpTl = (short*)take(L1SZ * 2);
  p.xah  = (short*)take(DOSZ * 2);
  p.xal  = (short*)take(DOSZ * 2);
  p.xaTh = (short*)take(DOSZ * 2);
  p.xaTl = (short*)take(DOSZ * 2);
  // final-stage aliases onto buffers dead at that point:
  // xf (1024x512 = MSZ_ elems) -> Ah/Al (2*ASZ_ == MSZ_ elems each): A is
  // dead after k5 of the last NS iter; k6-last reads only Bm/Xt/Xp.
  p.xfh  = p.Ah;
  p.xfl  = p.Al;
  // l1f (1024x1024 = 2*MSZ_ elems) -> Xpl0 / Xph1: dead after chunk loop
  // (k8a, which writes them, runs after the kernel boundary).
  p.l1fh = p.Xpl0;
  p.l1fl = p.Xph1;

  muon_init<<<2048, 256, 0, stream>>>(p);
  for (int c = 0; c < NCH_ - 1; c++) {
    muon_k1a<<<256, 256, 0, stream>>>(p);
    muon_k1b<<<128, 256, 0, stream>>>(p, c);
    muon_k1c<<<256, 256, 0, stream>>>(p);
    muon_k2<<<1024, 256, 0, stream>>>(p);
    for (int it = 0; it < 5; it++) {
      int cur = it & 1;
      muon_k4<<<272, 256, 0, stream>>>(p, cur, it == 0 ? 1 : 0);
      muon_k5<<<272, 256, 0, stream>>>(p);
      muon_k6<<<1024, 256, 0, stream>>>(p, cur, it == 0 ? 1 : 0,
                                        it == 4 ? 1 : 0, c + 1);
    }
  }
  muon_k8a<<<1024, 256, 0, stream>>>(p);
  muon_k8b<<<512, 256, 0, stream>>>(p);
}

// Round 10
// 16833.849 us; speedup vs baseline: 6.3273x; 1.0081x over previous
//
#include <hip/hip_runtime.h>

#define D_ 512
#define H_ 1024
#define L_ 4096
#define CS_ 64
#define NCH_ 64
#define RACT_ 256
#define LR_ 0.1f
#define MOM_ 0.95f
#define NSA_ 3.4445f
#define NSB_ (-4.7750f)
#define NSC_ 2.0315f

#define MSZ_ ((size_t)D_ * H_)
#define ASZ_ ((size_t)D_ * D_)

using bf16x8 = __attribute__((ext_vector_type(8))) short;
using f32x4  = __attribute__((ext_vector_type(4))) float;
using f32x2  = __attribute__((ext_vector_type(2))) float;
using s16x4  = __attribute__((ext_vector_type(4))) short;
using s16x2  = __attribute__((ext_vector_type(2))) short;

__device__ __forceinline__ short f2bs(float f) {
  unsigned u = __builtin_bit_cast(unsigned, f);
  unsigned r = (u + 0x7fffu + ((u >> 16) & 1u)) >> 16;  // RNE
  return (short)r;
}
__device__ __forceinline__ float bs2f(short s) {
  unsigned u = ((unsigned)(unsigned short)s) << 16;
  return __builtin_bit_cast(float, u);
}
__device__ __forceinline__ void split2(float v, short& h, short& l) {
  h = f2bs(v);
  l = f2bs(v - bs2f(h));
}

#define MFMA16(a, b, c) __builtin_amdgcn_mfma_f32_16x16x32_bf16(a, b, c, 0, 0, 0)

// MFMA core: one wave accumulates its K-slice of a 32x32 tile (2x2 frags).
__device__ __forceinline__ void mma_slice(
    const short* __restrict__ Ah, const short* __restrict__ Al, int lda,
    const short* __restrict__ Bh, const short* __restrict__ Bl, int ldb,
    int m0, int n0, int k0, int klen, int lm, int kq, f32x4 (&acc)[2][2]) {
  const size_t ao = (size_t)(m0 + lm) * lda + k0 + kq * 8;
  const size_t bo = (size_t)(n0 + lm) * ldb + k0 + kq * 8;
  const size_t ao1 = ao + (size_t)16 * lda;
  const size_t bo1 = bo + (size_t)16 * ldb;
#pragma unroll 4
  for (int k = 0; k < klen; k += 32) {
    bf16x8 ah0 = *(const bf16x8*)(Ah + ao + k);
    bf16x8 ah1 = *(const bf16x8*)(Ah + ao1 + k);
    bf16x8 bh0 = *(const bf16x8*)(Bh + bo + k);
    bf16x8 bh1 = *(const bf16x8*)(Bh + bo1 + k);
    bf16x8 al0 = *(const bf16x8*)(Al + ao + k);
    bf16x8 al1 = *(const bf16x8*)(Al + ao1 + k);
    bf16x8 bl0 = *(const bf16x8*)(Bl + bo + k);
    bf16x8 bl1 = *(const bf16x8*)(Bl + bo1 + k);
    acc[0][0] = MFMA16(ah0, bh0, acc[0][0]);
    acc[0][1] = MFMA16(ah0, bh1, acc[0][1]);
    acc[1][0] = MFMA16(ah1, bh0, acc[1][0]);
    acc[1][1] = MFMA16(ah1, bh1, acc[1][1]);
    acc[0][0] = MFMA16(ah0, bl0, acc[0][0]);
    acc[0][1] = MFMA16(ah0, bl1, acc[0][1]);
    acc[1][0] = MFMA16(ah1, bl0, acc[1][0]);
    acc[1][1] = MFMA16(ah1, bl1, acc[1][1]);
    acc[0][0] = MFMA16(al0, bh0, acc[0][0]);
    acc[0][1] = MFMA16(al0, bh1, acc[0][1]);
    acc[1][0] = MFMA16(al1, bh0, acc[1][0]);
    acc[1][1] = MFMA16(al1, bh1, acc[1][1]);
  }
}

__device__ __forceinline__ void spill_acc(float (*lds)[32][32], int w, int lm,
                                          int kq, const f32x4 (&acc)[2][2]) {
#pragma unroll
  for (int i = 0; i < 2; i++)
#pragma unroll
    for (int j = 0; j < 2; j++)
#pragma unroll
      for (int e = 0; e < 4; e++)
        lds[w][i * 16 + kq * 4 + e][j * 16 + lm] = acc[i][j][e];
}

// 4-wave (256-thread) split-K GEMM; 4 outputs/thread at (row, c0..c0+3).
template <int K>
__device__ __forceinline__ f32x4 gemm_ks(
    const short* __restrict__ Ah, const short* __restrict__ Al, int lda,
    const short* __restrict__ Bh, const short* __restrict__ Bl, int ldb,
    int m0, int n0, float (*lds)[32][32], int& row, int& c0) {
  const int tid = threadIdx.x;
  const int w = tid >> 6, lane = tid & 63;
  const int lm = lane & 15, kq = lane >> 4;
  constexpr int KQ = K >> 2;
  f32x4 z = {0.f, 0.f, 0.f, 0.f};
  f32x4 acc[2][2] = {{z, z}, {z, z}};
  mma_slice(Ah, Al, lda, Bh, Bl, ldb, m0, n0, w * KQ, KQ, lm, kq, acc);
  spill_acc(lds, w, lm, kq, acc);
  __syncthreads();
  row = tid >> 3;
  c0 = (tid & 7) * 4;
  f32x4 s = *(const f32x4*)&lds[0][row][c0];
  s += *(const f32x4*)&lds[1][row][c0];
  s += *(const f32x4*)&lds[2][row][c0];
  s += *(const f32x4*)&lds[3][row][c0];
  return s;
}

// 8-wave (512-thread) split-K GEMM; 2 outputs/thread at (row, c0..c0+1).
template <int K>
__device__ __forceinline__ f32x2 gemm_ks8(
    const short* __restrict__ Ah, const short* __restrict__ Al, int lda,
    const short* __restrict__ Bh, const short* __restrict__ Bl, int ldb,
    int m0, int n0, float (*lds)[32][32], int& row, int& c0) {
  const int tid = threadIdx.x;
  const int w = tid >> 6, lane = tid & 63;
  const int lm = lane & 15, kq = lane >> 4;
  constexpr int KQ = K >> 3;
  f32x4 z = {0.f, 0.f, 0.f, 0.f};
  f32x4 acc[2][2] = {{z, z}, {z, z}};
  mma_slice(Ah, Al, lda, Bh, Bl, ldb, m0, n0, w * KQ, KQ, lm, kq, acc);
  spill_acc(lds, w, lm, kq, acc);
  __syncthreads();
  row = tid >> 4;
  c0 = (tid & 15) * 2;
  f32x2 s = *(const f32x2*)&lds[0][row][c0];
#pragma unroll
  for (int ww = 1; ww < 8; ww++) s += *(const f32x2*)&lds[ww][row][c0];
  return s;
}

#define GEMM_SHARED __shared__ float lds[4][32][32];
#define GEMM_SHARED8 __shared__ float lds8[8][32][32];

// Coalesced transposed store of a 32x32 split-bf16 tile (256-thread form).
__device__ __forceinline__ void store_T(
    void* ldsraw, int row, int c0, const s16x4& hv, const s16x4& lv,
    short* __restrict__ th, short* __restrict__ tl, int ldt, int m0, int n0) {
  short (*sh)[36] = (short(*)[36])ldsraw;
  short (*sl)[36] = (short(*)[36])ldsraw + 32;
  __syncthreads();
#pragma unroll
  for (int cc = 0; cc < 4; cc++) {
    sh[row][c0 + cc] = hv[cc];
    sl[row][c0 + cc] = lv[cc];
  }
  __syncthreads();
  const int tr = threadIdx.x >> 3;
  const int tc = (threadIdx.x & 7) * 4;
  s16x4 oh, ol;
#pragma unroll
  for (int j = 0; j < 4; j++) { oh[j] = sh[tc + j][tr]; ol[j] = sl[tc + j][tr]; }
  *(s16x4*)&th[(size_t)(n0 + tr) * ldt + m0 + tc] = oh;
  *(s16x4*)&tl[(size_t)(n0 + tr) * ldt + m0 + tc] = ol;
}

// 512-thread form: 2 elems/thread in, 2 elems/thread out.
__device__ __forceinline__ void store_T2(
    void* ldsraw, int row, int c0, const s16x2& hv, const s16x2& lv,
    short* __restrict__ th, short* __restrict__ tl, int ldt, int m0, int n0) {
  short (*sh)[36] = (short(*)[36])ldsraw;
  short (*sl)[36] = (short(*)[36])ldsraw + 32;
  __syncthreads();
  sh[row][c0] = hv[0]; sh[row][c0 + 1] = hv[1];
  sl[row][c0] = lv[0]; sl[row][c0 + 1] = lv[1];
  __syncthreads();
  const int tr = threadIdx.x >> 4;
  const int tc = (threadIdx.x & 15) * 2;
  s16x2 oh, ol;
  oh[0] = sh[tc][tr]; oh[1] = sh[tc + 1][tr];
  ol[0] = sl[tc][tr]; ol[1] = sl[tc + 1][tr];
  *(s16x2*)&th[(size_t)(n0 + tr) * ldt + m0 + tc] = oh;
  *(s16x2*)&tl[(size_t)(n0 + tr) * ldt + m0 + tc] = ol;
}

struct P {
  const float *kin, *vin, *w1in, *w2in;
  float *w1f, *w2f /* stored TRANSPOSED: [d][h] */, *buf1, *buf2t, *deriv, *partial;
  short *w1bth, *w1btl, *w2bh, *w2bl, *w2bth, *w2btl;
  short *Xph0, *Xpl0, *Xth0, *Xtl0, *Xph1, *Xpl1, *Xth1, *Xtl1;
  short *Ah, *Al, *Bmh, *Bml;
  short *l1h, *l1l, *l1Th, *l1Tl, *dOh, *dOl, *dOTh, *dOTl, *dpTh, *dpTl;
  short *xah, *xal, *xaTh, *xaTl;
  short *xfh, *xfl, *l1fh, *l1fl;   // xf* alias Ah/Al; l1f* alias Xpl0/Xph1
  float *out;
};

// deterministic reduce of k2 partials (256-thread blocks)
__device__ __forceinline__ void norm_scales(const float* __restrict__ partial,
                                            float* snorm, float* sred) {
  const int t = threadIdx.x;
#pragma unroll
  for (int jb = 0; jb < 2; jb++) {
    float v = partial[jb * 512 + t] + partial[jb * 512 + 256 + t];
    for (int off = 32; off > 0; off >>= 1) v += __shfl_down(v, off, 64);
    if ((t & 63) == 0) sred[t >> 6] = v;
    __syncthreads();
    if (t == 0)
      snorm[jb] = 1.f / (sqrtf(sred[0] + sred[1] + sred[2] + sred[3]) + 1e-7f);
    __syncthreads();
  }
}

// deterministic reduce of k2 partials (512-thread blocks)
__device__ __forceinline__ void norm_scales512(const float* __restrict__ partial,
                                               float* snorm, float* sred) {
  const int t = threadIdx.x;
#pragma unroll
  for (int jb = 0; jb < 2; jb++) {
    float v = partial[jb * 512 + t];
    for (int off = 32; off > 0; off >>= 1) v += __shfl_down(v, off, 64);
    if ((t & 63) == 0) sred[t >> 6] = v;
    __syncthreads();
    if (t == 0) {
      float s = 0.f;
#pragma unroll
      for (int kk = 0; kk < 8; kk++) s += sred[kk];
      snorm[jb] = 1.f / (sqrtf(s) + 1e-7f);
    }
    __syncthreads();
  }
}

// gather + split active rows (256x512) of chunk c (grid-stride)
__device__ __forceinline__ void kx_body(const P& p, int c) {
  for (int idx = blockIdx.x * blockDim.x + threadIdx.x; idx < RACT_ * D_;
       idx += gridDim.x * blockDim.x) {
    int r = idx >> 9, d = idx & 511;
    int b = r >> 4, t = r & 15;
    float v = p.kin[(size_t)(b * L_ + c * CS_ + t) * D_ + d];
    short h, l; split2(v, h, l);
    p.xah[idx] = h; p.xal[idx] = l;
    p.xaTh[(size_t)d * RACT_ + r] = h; p.xaTl[(size_t)d * RACT_ + r] = l;
  }
}

// gather + split full last chunk (1024x512) (grid-stride)
__device__ __forceinline__ void kxf_body(const P& p) {
  for (int idx = blockIdx.x * blockDim.x + threadIdx.x; idx < (int)MSZ_;
       idx += gridDim.x * blockDim.x) {
    int r = idx >> 9, d = idx & 511;
    int b = r >> 6, t = r & 63;
    float v = p.kin[(size_t)(b * L_ + (NCH_ - 1) * CS_ + t) * D_ + d];
    short h, l; split2(v, h, l);
    p.xfh[idx] = h; p.xfl[idx] = l;
  }
}

// ---------------- init: weights, split mirrors, momentum, kx(0) -------------
__global__ __launch_bounds__(256) void muon_init(P p) {
  int idx = blockIdx.x * 256 + threadIdx.x;  // grid 2048 -> MSZ_ threads
  float a = p.w1in[idx], b = p.w2in[idx];
  p.w1f[idx] = a;
  p.buf1[idx] = 0.f; p.buf2t[idx] = 0.f;
  short h, l;
  int d1 = idx >> 10, h1 = idx & 1023;        // w1 [d][h]
  split2(a, h, l);
  p.w1bth[(size_t)h1 * D_ + d1] = h; p.w1btl[(size_t)h1 * D_ + d1] = l;
  int h2 = idx >> 9, d2 = idx & 511;          // w2 input [h][d]
  p.w2f[(size_t)d2 * H_ + h2] = b;            // w2f stored transposed [d][h]
  split2(b, h, l);
  p.w2bh[idx] = h; p.w2bl[idx] = l;
  p.w2bth[(size_t)d2 * H_ + h2] = h; p.w2btl[(size_t)d2 * H_ + h2] = l;
  if (idx < RACT_ * D_) {  // kx(0)
    int r = idx >> 9, d = idx & 511;
    int b2 = r >> 4, t = r & 15;
    float v = p.kin[(size_t)(b2 * L_ + t) * D_ + d];
    split2(v, h, l);
    p.xah[idx] = h; p.xal[idx] = l;
    p.xaTh[(size_t)d * RACT_ + r] = h; p.xaTl[(size_t)d * RACT_ + r] = l;
  }
}

// ---------------- k1a: l1 = tanh(x @ w1); grid 256 x 512thr -----------------
__global__ __launch_bounds__(512, 2) void muon_k1a(P p) {
  GEMM_SHARED8
  const int m0 = (blockIdx.x >> 5) * 32, n0 = (blockIdx.x & 31) * 32;
  int row, c0;
  f32x2 s = gemm_ks8<D_>(p.xah, p.xal, D_, p.w1bth, p.w1btl, D_,
                         m0, n0, lds8, row, c0);
  int gm = m0 + row, gn0 = n0 + c0;
  s16x2 hv, lv; f32x2 dv;
#pragma unroll
  for (int cc = 0; cc < 2; cc++) {
    float l1v = tanhf(s[cc]);
    short h, l; split2(l1v, h, l);
    hv[cc] = h; lv[cc] = l; dv[cc] = 1.f - l1v * l1v;
  }
  *(s16x2*)&p.l1h[(size_t)gm * H_ + gn0] = hv;
  *(s16x2*)&p.l1l[(size_t)gm * H_ + gn0] = lv;
  *(f32x2*)&p.deriv[(size_t)gm * H_ + gn0] = dv;
  store_T2(lds8, row, c0, hv, lv, p.l1Th, p.l1Tl, RACT_, m0, n0);
}

// ---------------- k1b: dOut = mask*2/1024*(l1@w2 - vt); grid 128 x 512thr ---
__global__ __launch_bounds__(512, 2) void muon_k1b(P p, int c) {
  GEMM_SHARED8
  const int m0 = (blockIdx.x >> 4) * 32, n0 = (blockIdx.x & 15) * 32;
  int row, c0;
  f32x2 s = gemm_ks8<H_>(p.l1h, p.l1l, H_, p.w2bth, p.w2btl, H_,
                         m0, n0, lds8, row, c0);
  int gm = m0 + row, gn0 = n0 + c0;
  int b = gm >> 4, t = gm & 15;
  bool mk = (t <= b) && (b - t <= 7);
  f32x2 vt2 = {0.f, 0.f};
  if (mk) vt2 = *(const f32x2*)&p.vin[(size_t)(b * L_ + c * CS_ + t) * D_ + gn0];
  s16x2 hv, lv;
#pragma unroll
  for (int cc = 0; cc < 2; cc++) {
    float dv = mk ? (2.0f / 1024.0f) * (s[cc] - vt2[cc]) : 0.f;
    short h, l; split2(dv, h, l);
    hv[cc] = h; lv[cc] = l;
  }
  *(s16x2*)&p.dOh[(size_t)gm * D_ + gn0] = hv;
  *(s16x2*)&p.dOl[(size_t)gm * D_ + gn0] = lv;
  store_T2(lds8, row, c0, hv, lv, p.dOTh, p.dOTl, RACT_, m0, n0);
}

// ---------------- k1c: dpre = (dOut @ w2^T) * deriv; grid 256 x 512thr ------
__global__ __launch_bounds__(512, 2) void muon_k1c(P p) {
  GEMM_SHARED8
  const int m0 = (blockIdx.x >> 5) * 32, n0 = (blockIdx.x & 31) * 32;
  int row, c0;
  f32x2 s = gemm_ks8<D_>(p.dOh, p.dOl, D_, p.w2bh, p.w2bl, D_,
                         m0, n0, lds8, row, c0);
  int gm = m0 + row, gn0 = n0 + c0;
  f32x2 dv = *(const f32x2*)&p.deriv[(size_t)gm * H_ + gn0];
  s16x2 hv, lv;
#pragma unroll
  for (int cc = 0; cc < 2; cc++) {
    float dp = s[cc] * dv[cc];
    short h, l; split2(dp, h, l);
    hv[cc] = h; lv[cc] = l;
  }
  store_T2(lds8, row, c0, hv, lv, p.dpTh, p.dpTl, RACT_, m0, n0);
}

// ---------------- k2: grads+momentum+nesterov -> split X0 planes; grid 1024 -
__global__ __launch_bounds__(256, 4) void muon_k2(P p) {
  GEMM_SHARED
  __shared__ float sred[4];
  const int bid = blockIdx.x;
  const int job = bid >> 9, tt = bid & 511;
  const int m0 = (tt >> 5) * 32, n0 = (tt & 31) * 32;
  const short* Ah_ = job ? p.dOTh : p.xaTh;
  const short* Al_ = job ? p.dOTl : p.xaTl;
  const short* Bh_ = job ? p.l1Th : p.dpTh;
  const short* Bl_ = job ? p.l1Tl : p.dpTl;
  float* buf = job ? p.buf2t : p.buf1;
  short* xph = p.Xph0 + (size_t)job * MSZ_;
  short* xpl = p.Xpl0 + (size_t)job * MSZ_;
  int row, c0;
  f32x4 s = gemm_ks<RACT_>(Ah_, Al_, RACT_, Bh_, Bl_, RACT_, m0, n0, lds, row, c0);
  int gm = m0 + row, gn0 = n0 + c0;
  size_t idx0 = (size_t)gm * H_ + gn0;
  f32x4 bv = *(const f32x4*)&buf[idx0];
  s16x4 hv, lv;
  float part = 0.f;
#pragma unroll
  for (int cc = 0; cc < 4; cc++) {
    float bn = MOM_ * bv[cc] + s[cc];
    bv[cc] = bn;
    float g = s[cc] + MOM_ * bn;  // nesterov (unnormalized X0)
    short h, l; split2(g, h, l);
    hv[cc] = h; lv[cc] = l;
    part += g * g;
  }
  *(f32x4*)&buf[idx0] = bv;
  *(s16x4*)&xph[idx0] = hv;
  *(s16x4*)&xpl[idx0] = lv;
  store_T(lds, row, c0, hv, lv, p.Xth0 + (size_t)job * MSZ_,
          p.Xtl0 + (size_t)job * MSZ_, D_, m0, n0);
  for (int off = 32; off > 0; off >>= 1) part += __shfl_down(part, off, 64);
  if ((threadIdx.x & 63) == 0) sred[threadIdx.x >> 6] = part;
  __syncthreads();
  if (threadIdx.x == 0) p.partial[bid] = sred[0] + sred[1] + sred[2] + sred[3];
}

// ---------------- k4: A = (s^2 at it0) * X@X^T; grid 272 x 512thr -----------
__global__ __launch_bounds__(512, 2) void muon_k4(P p, int cur, int it0) {
  GEMM_SHARED8
  __shared__ float sred[8];
  __shared__ float snorm[2];
  if (it0) norm_scales512(p.partial, snorm, sred);
  const int bid = blockIdx.x;            // 2 jobs x 136 lower-tri tiles
  const int job = bid >= 136;
  int tt = job ? bid - 136 : bid;
  int mt = 0;
  while (tt >= 16 - mt) { tt -= 16 - mt; mt++; }
  const int nt = mt + tt;
  const int m0 = mt * 32, n0 = nt * 32;
  const short* Xph_ = cur ? p.Xph1 : p.Xph0;
  const short* Xpl_ = cur ? p.Xpl1 : p.Xpl0;
  const short* xh = Xph_ + (size_t)job * MSZ_;
  const short* xl = Xpl_ + (size_t)job * MSZ_;
  int row, c0;
  f32x2 s = gemm_ks8<H_>(xh, xl, H_, xh, xl, H_, m0, n0, lds8, row, c0);
  int gm = m0 + row, gn0 = n0 + c0;
  float sc = it0 ? (job ? snorm[1] * snorm[1] : snorm[0] * snorm[0]) : 1.f;
  short* ah = p.Ah + (size_t)job * ASZ_;
  short* al = p.Al + (size_t)job * ASZ_;
  s16x2 hv, lv;
#pragma unroll
  for (int cc = 0; cc < 2; cc++) {
    short h, l; split2(sc * s[cc], h, l);
    hv[cc] = h; lv[cc] = l;
  }
  *(s16x2*)&ah[(size_t)gm * D_ + gn0] = hv;
  *(s16x2*)&al[(size_t)gm * D_ + gn0] = lv;
  if (mt != nt) store_T2(lds8, row, c0, hv, lv, ah, al, D_, m0, n0);  // mirror
}

// ---------------- k5: Bm = b*A + c*(A@A); grid 272 x 512thr -----------------
__global__ __launch_bounds__(512, 2) void muon_k5(P p) {
  GEMM_SHARED8
  const int bid = blockIdx.x;
  const int job = bid >= 136;
  int tt = job ? bid - 136 : bid;
  int mt = 0;
  while (tt >= 16 - mt) { tt -= 16 - mt; mt++; }
  const int nt = mt + tt;
  const int m0 = mt * 32, n0 = nt * 32;
  const short* ah = p.Ah + (size_t)job * ASZ_;
  const short* al = p.Al + (size_t)job * ASZ_;
  int row, c0;
  f32x2 s = gemm_ks8<D_>(ah, al, D_, ah, al, D_, m0, n0, lds8, row, c0);  // A sym
  int gm = m0 + row, gn0 = n0 + c0;
  s16x2 ahv = *(const s16x2*)&ah[(size_t)gm * D_ + gn0];
  s16x2 alv = *(const s16x2*)&al[(size_t)gm * D_ + gn0];
  short* bh = p.Bmh + (size_t)job * ASZ_;
  short* bl = p.Bml + (size_t)job * ASZ_;
  s16x2 hv, lv;
#pragma unroll
  for (int cc = 0; cc < 2; cc++) {
    float av = bs2f(ahv[cc]) + bs2f(alv[cc]);
    short h, l; split2(NSB_ * av + NSC_ * s[cc], h, l);
    hv[cc] = h; lv[cc] = l;
  }
  *(s16x2*)&bh[(size_t)gm * D_ + gn0] = hv;
  *(s16x2*)&bl[(size_t)gm * D_ + gn0] = lv;
  if (mt != nt) store_T2(lds8, row, c0, hv, lv, bh, bl, D_, m0, n0);  // mirror
}

// ---------------- k6: Xn = (s at it0)*(a*X + Bm@X); grid 1024 ---------------
// last: weight update + fold next chunk's gather (kx / kxf).
__global__ __launch_bounds__(256, 4) void muon_k6(P p, int cur, int it0,
                                                  int last, int cnext) {
  GEMM_SHARED
  __shared__ float sred[4];
  __shared__ float snorm[2];
  if (it0) norm_scales(p.partial, snorm, sred);
  const int bid = blockIdx.x;
  const int job = bid >> 9, tt = bid & 511;
  const int m0 = (tt >> 5) * 32, n0 = (tt & 31) * 32;
  const short* Xph_ = cur ? p.Xph1 : p.Xph0;
  const short* Xpl_ = cur ? p.Xpl1 : p.Xpl0;
  const short* Xth_ = cur ? p.Xth1 : p.Xth0;
  const short* Xtl_ = cur ? p.Xtl1 : p.Xtl0;
  short* XphN = cur ? p.Xph0 : p.Xph1;
  short* XplN = cur ? p.Xpl0 : p.Xpl1;
  short* XthN = cur ? p.Xth0 : p.Xth1;
  short* XtlN = cur ? p.Xtl0 : p.Xtl1;
  const short* bmh = p.Bmh + (size_t)job * ASZ_;
  const short* bml = p.Bml + (size_t)job * ASZ_;
  int row, c0;
  f32x4 s = gemm_ks<D_>(bmh, bml, D_, Xth_ + job * MSZ_, Xtl_ + job * MSZ_,
                        D_, m0, n0, lds, row, c0);
  int gm = m0 + row, gn0 = n0 + c0;
  size_t idx0 = (size_t)gm * H_ + gn0;
  float scl = it0 ? (job ? snorm[1] : snorm[0]) : 1.f;
  s16x4 ph = *(const s16x4*)&Xph_[job * MSZ_ + idx0];
  s16x4 pl = *(const s16x4*)&Xpl_[job * MSZ_ + idx0];
  f32x4 xv;
#pragma unroll
  for (int cc = 0; cc < 4; cc++)
    xv[cc] = scl * (NSA_ * (bs2f(ph[cc]) + bs2f(pl[cc])) + s[cc]);
  if (!last) {
    s16x4 hv, lv;
#pragma unroll
    for (int cc = 0; cc < 4; cc++) {
      short h, l; split2(xv[cc], h, l);
      hv[cc] = h; lv[cc] = l;
    }
    *(s16x4*)&XphN[job * MSZ_ + idx0] = hv;
    *(s16x4*)&XplN[job * MSZ_ + idx0] = lv;
    store_T(lds, row, c0, hv, lv, XthN + job * MSZ_, XtlN + job * MSZ_,
            D_, m0, n0);
  } else if (job == 0) {
    f32x4 wv = *(const f32x4*)&p.w1f[idx0];
    s16x4 hv, lv;
#pragma unroll
    for (int cc = 0; cc < 4; cc++) {
      float nv = wv[cc] - LR_ * xv[cc];   // w1 [d][h] == X1 orientation
      wv[cc] = nv;
      short h, l; split2(nv, h, l);
      hv[cc] = h; lv[cc] = l;
    }
    *(f32x4*)&p.w1f[idx0] = wv;
    store_T(lds, row, c0, hv, lv, p.w1bth, p.w1btl, D_, m0, n0);
  } else {
    // w2f stored transposed [d][h]: contiguous at idx0. u2 = X2^T.
    f32x4 wv = *(const f32x4*)&p.w2f[idx0];
    s16x4 hv, lv;
#pragma unroll
    for (int cc = 0; cc < 4; cc++) {
      float nv = wv[cc] - LR_ * xv[cc];
      wv[cc] = nv;
      short h, l; split2(nv, h, l);
      hv[cc] = h; lv[cc] = l;
    }
    *(f32x4*)&p.w2f[idx0] = wv;
    *(s16x4*)&p.w2bth[idx0] = hv;
    *(s16x4*)&p.w2btl[idx0] = lv;
    store_T(lds, row, c0, hv, lv, p.w2bh, p.w2bl, D_, m0, n0);
  }
  if (last) {  // gather next chunk's x (no dep on this kernel's outputs)
    if (cnext < NCH_ - 1) kx_body(p, cnext);
    else kxf_body(p);
  }
}

// ---------------- k8a: final forward layer 1; grid 1024 ---------------------
__global__ __launch_bounds__(256, 4) void muon_k8a(P p) {
  GEMM_SHARED
  const int m0 = (blockIdx.x >> 5) * 32, n0 = (blockIdx.x & 31) * 32;
  int row, c0;
  f32x4 s = gemm_ks<D_>(p.xfh, p.xfl, D_, p.w1bth, p.w1btl, D_,
                        m0, n0, lds, row, c0);
  int gm = m0 + row, gn0 = n0 + c0;
  s16x4 hv, lv;
#pragma unroll
  for (int cc = 0; cc < 4; cc++) {
    short h, l; split2(tanhf(s[cc]), h, l);
    hv[cc] = h; lv[cc] = l;
  }
  *(s16x4*)&p.l1fh[(size_t)gm * H_ + gn0] = hv;
  *(s16x4*)&p.l1fl[(size_t)gm * H_ + gn0] = lv;
}

// ---------------- k8b: final forward layer 2 -> out; grid 512 ---------------
__global__ __launch_bounds__(256, 4) void muon_k8b(P p) {
  GEMM_SHARED
  const int m0 = (blockIdx.x >> 4) * 32, n0 = (blockIdx.x & 15) * 32;
  int row, c0;
  f32x4 s = gemm_ks<H_>(p.l1fh, p.l1fl, H_, p.w2bth, p.w2btl, H_,
                        m0, n0, lds, row, c0);
  int gm = m0 + row, gn0 = n0 + c0;
  *(f32x4*)&p.out[(size_t)gm * D_ + gn0] = s;
}

extern "C" void kernel_launch(void* const* d_in, const int* in_sizes, int n_in,
                              void* d_out, int out_size, void* d_ws, size_t ws_size,
                              hipStream_t stream) {
  char* pp = (char*)d_ws;
  auto take = [&](size_t bytes) {
    char* r = pp; pp += (bytes + 255) & ~(size_t)255; return r;
  };
  const size_t L1SZ = (size_t)RACT_ * H_;
  const size_t DOSZ = (size_t)RACT_ * D_;

  P p;
  p.kin  = (const float*)d_in[0];
  p.vin  = (const float*)d_in[1];
  p.w1in = (const float*)d_in[2];
  p.w2in = (const float*)d_in[3];
  p.out  = (float*)d_out;

  p.w1f   = (float*)take(MSZ_ * 4);
  p.w2f   = (float*)take(MSZ_ * 4);
  p.buf1  = (float*)take(MSZ_ * 4);
  p.buf2t = (float*)take(MSZ_ * 4);
  p.deriv = (float*)take(L1SZ * 4);
  p.partial = (float*)take(1024 * 4);
  p.w1bth = (short*)take(MSZ_ * 2);
  p.w1btl = (short*)take(MSZ_ * 2);
  p.w2bh  = (short*)take(MSZ_ * 2);
  p.w2bl  = (short*)take(MSZ_ * 2);
  p.w2bth = (short*)take(MSZ_ * 2);
  p.w2btl = (short*)take(MSZ_ * 2);
  p.Xph0 = (short*)take(2 * MSZ_ * 2);
  p.Xpl0 = (short*)take(2 * MSZ_ * 2);
  p.Xth0 = (short*)take(2 * MSZ_ * 2);
  p.Xtl0 = (short*)take(2 * MSZ_ * 2);
  p.Xph1 = (short*)take(2 * MSZ_ * 2);
  p.Xpl1 = (short*)take(2 * MSZ_ * 2);
  p.Xth1 = (short*)take(2 * MSZ_ * 2);
  p.Xtl1 = (short*)take(2 * MSZ_ * 2);
  p.Ah  = (short*)take(2 * ASZ_ * 2);
  p.Al  = (short*)take(2 * ASZ_ * 2);
  p.Bmh = (short*)take(2 * ASZ_ * 2);
  p.Bml = (short*)take(2 * ASZ_ * 2);
  p.l1h  = (short*)take(L1SZ * 2);
  p.l1l  = (short*)take(L1SZ * 2);
  p.l1Th = (short*)take(L1SZ * 2);
  p.l1Tl = (short*)take(L1SZ * 2);
  p.dOh  = (short*)take(DOSZ * 2);
  p.dOl  = (short*)take(DOSZ * 2);
  p.dOTh = (short*)take(DOSZ * 2);
  p.dOTl = (short*)take(DOSZ * 2);
  p.dpTh = (short*)take(L1SZ * 2);
  p.dpTl = (short*)take(L1SZ * 2);
  p.xah  = (short*)take(DOSZ * 2);
  p.xal  = (short*)take(DOSZ * 2);
  p.xaTh = (short*)take(DOSZ * 2);
  p.xaTl = (short*)take(DOSZ * 2);
  // final-stage aliases onto buffers dead at that point:
  // xf (1024x512 = MSZ_ elems) -> Ah/Al (2*ASZ_ == MSZ_ elems each): A is
  // dead after k5 of the last NS iter; k6-last reads only Bm/Xt/Xp.
  p.xfh  = p.Ah;
  p.xfl  = p.Al;
  // l1f (1024x1024 = 2*MSZ_ elems) -> Xpl0 / Xph1: dead after chunk loop
  // (k8a, which writes them, runs after the kernel boundary).
  p.l1fh = p.Xpl0;
  p.l1fl = p.Xph1;

  muon_init<<<2048, 256, 0, stream>>>(p);
  for (int c = 0; c < NCH_ - 1; c++) {
    muon_k1a<<<256, 512, 0, stream>>>(p);
    muon_k1b<<<128, 512, 0, stream>>>(p, c);
    muon_k1c<<<256, 512, 0, stream>>>(p);
    muon_k2<<<1024, 256, 0, stream>>>(p);
    for (int it = 0; it < 5; it++) {
      int cur = it & 1;
      muon_k4<<<272, 512, 0, stream>>>(p, cur, it == 0 ? 1 : 0);
      muon_k5<<<272, 512, 0, stream>>>(p);
      muon_k6<<<1024, 256, 0, stream>>>(p, cur, it == 0 ? 1 : 0,
                                        it == 4 ? 1 : 0, c + 1);
    }
  }
  muon_k8a<<<1024, 256, 0, stream>>>(p);
  muon_k8b<<<512, 256, 0, stream>>>(p);
}